// Round 1
// baseline (855.473 us; speedup 1.0000x reference)
//
#include <hip/hip_runtime.h>
#include <math.h>

#define DIN 18
#define HID 128
#define NEGS 0.2f
#define BN_EPS 1e-5f

__device__ __forceinline__ float leaky(float x){ return x >= 0.f ? x : NEGS * x; }

__device__ __forceinline__ float wred_sum(float v){
  #pragma unroll
  for (int off = 32; off; off >>= 1) v += __shfl_xor(v, off);
  return v;
}
__device__ __forceinline__ float wred_max(float v){
  #pragma unroll
  for (int off = 32; off; off >>= 1) v = fmaxf(v, __shfl_xor(v, off));
  return v;
}

// ---------------- CSR build ----------------
__global__ void k_deg(const int* __restrict__ row, int* __restrict__ deg, int E){
  int i = blockIdx.x * blockDim.x + threadIdx.x;
  if (i < E) atomicAdd(&deg[row[i]], 1);
}

__global__ void k_scan(const int* __restrict__ deg, int* __restrict__ rowptr, int n){
  __shared__ int buf[1024];
  __shared__ int s_carry;
  int tid = threadIdx.x;
  if (tid == 0){ s_carry = 0; rowptr[0] = 0; }
  __syncthreads();
  for (int base = 0; base < n; base += 1024){
    int i = base + tid;
    int v = (i < n) ? deg[i] : 0;
    buf[tid] = v;
    __syncthreads();
    #pragma unroll
    for (int off = 1; off < 1024; off <<= 1){
      int t = (tid >= off) ? buf[tid - off] : 0;
      __syncthreads();
      buf[tid] += t;
      __syncthreads();
    }
    int incl = buf[tid] + s_carry;
    if (i < n) rowptr[i + 1] = incl;
    __syncthreads();
    if (tid == 0) s_carry += buf[1023];
    __syncthreads();
  }
}

__global__ void k_fill(const int* __restrict__ row, const int* __restrict__ col,
                       const int* __restrict__ rowptr, int* __restrict__ cursor,
                       int* __restrict__ cols_s, int E){
  int i = blockIdx.x * blockDim.x + threadIdx.x;
  if (i < E){
    int r = row[i];
    int p = atomicAdd(&cursor[r], 1);
    cols_s[rowptr[r] + p] = col[i];
  }
}

// ---------------- neighbor mean ----------------
__global__ void k_nmean(const float* __restrict__ x, const int* __restrict__ rowptr,
                        const int* __restrict__ cols, float* __restrict__ nmean, int n){
  int node = blockIdx.x * 4 + (threadIdx.x >> 6);
  if (node >= n) return;
  int lane = threadIdx.x & 63;
  int s = rowptr[node], e = rowptr[node + 1];
  if (lane < DIN){
    float acc = 0.f;
    for (int j = s; j < e; ++j){
      int c = cols[j];
      acc += x[c * DIN + lane];
    }
    float d = (float)(e - s);
    nmean[node * DIN + lane] = acc / (d + 1e-8f);
  }
}

// ---------------- input projection: h = x@Win + nmean@Wagg + biases ----------------
__global__ void k_h_in(const float* __restrict__ x, const float* __restrict__ nmean,
                       const float* __restrict__ Win, const float* __restrict__ bin,
                       const float* __restrict__ Wagg, const float* __restrict__ bagg,
                       float* __restrict__ out, int n){
  int i = blockIdx.x * blockDim.x + threadIdx.x;
  if (i >= n * HID) return;
  int node = i >> 7, c = i & 127;
  float acc = bin[c] + bagg[c];
  const float* xr = &x[node * DIN];
  const float* nr = &nmean[node * DIN];
  #pragma unroll
  for (int d = 0; d < DIN; ++d){
    acc += xr[d] * Win[d * HID + c] + nr[d] * Wagg[d * HID + c];
  }
  out[i] = acc;
}

// ---------------- generic 128x128 GEMM, 16 nodes/block ----------------
// mode 0: out = src@W + b ; mode 1: out = leaky(src@W + b)
__global__ void k_gemm128(const float* __restrict__ src, const float* __restrict__ W,
                          const float* __restrict__ bias, float* __restrict__ dst,
                          int n, int mode){
  __shared__ float hs[16][HID];
  int tid = threadIdx.x;
  int base = blockIdx.x * 16;
  #pragma unroll
  for (int k = 0; k < 16; ++k){
    int nd = base + k;
    hs[k][tid] = (nd < n) ? src[nd * HID + tid] : 0.f;
  }
  __syncthreads();
  float acc[16];
  #pragma unroll
  for (int k = 0; k < 16; ++k) acc[k] = 0.f;
  for (int d = 0; d < HID; ++d){
    float w = W[d * HID + tid];
    #pragma unroll
    for (int k = 0; k < 16; ++k) acc[k] += hs[k][d] * w;
  }
  float b = bias[tid];
  #pragma unroll
  for (int k = 0; k < 16; ++k){
    int nd = base + k;
    if (nd < n){
      float v = acc[k] + b;
      if (mode == 1) v = leaky(v);
      dst[nd * HID + tid] = v;
    }
  }
}

// ---------------- rearrange mh_Wv [4][128][32] -> Wcat [128][128] ----------------
__global__ void k_rearr(const float* __restrict__ mhWv, float* __restrict__ Wcat){
  int i = blockIdx.x * blockDim.x + threadIdx.x;
  if (i >= HID * HID) return;
  int d = i >> 7, c = i & 127;
  Wcat[i] = mhWv[((c >> 5) * HID + d) * 32 + (c & 31)];
}

// ---------------- single-head scores ----------------
__global__ void k_scores_sh(const float* __restrict__ h, const float* __restrict__ asrc,
                            const float* __restrict__ adst,
                            float* __restrict__ ssrc, float* __restrict__ sdst, int n){
  int node = blockIdx.x * 4 + (threadIdx.x >> 6);
  if (node >= n) return;
  int lane = threadIdx.x & 63;
  float h0 = h[node * HID + lane], h1 = h[node * HID + 64 + lane];
  float ps = h0 * asrc[lane] + h1 * asrc[64 + lane];
  float pd = h0 * adst[lane] + h1 * adst[64 + lane];
  ps = wred_sum(ps);
  pd = wred_sum(pd);
  if (lane == 0){ ssrc[node] = ps; sdst[node] = pd; }
}

// ---------------- multi-head scores ----------------
__global__ void k_scores_mh(const float* __restrict__ h, const float* __restrict__ asrc,
                            const float* __restrict__ adst,
                            float* __restrict__ ssrc, float* __restrict__ sdst, int n){
  int node = blockIdx.x * 4 + (threadIdx.x >> 6);
  if (node >= n) return;
  int lane = threadIdx.x & 63;
  float h0 = h[node * HID + lane], h1 = h[node * HID + 64 + lane];
  #pragma unroll
  for (int hd = 0; hd < 4; ++hd){
    float ps = h0 * asrc[hd * HID + lane] + h1 * asrc[hd * HID + 64 + lane];
    float pd = h0 * adst[hd * HID + lane] + h1 * adst[hd * HID + 64 + lane];
    ps = wred_sum(ps);
    pd = wred_sum(pd);
    if (lane == 0){ ssrc[node * 4 + hd] = ps; sdst[node * 4 + hd] = pd; }
  }
}

// ---------------- single-head aggregation + BN + (residual) + leaky ----------------
__global__ void k_agg_sh(const int* __restrict__ rowptr, const int* __restrict__ cols,
                         const float* __restrict__ ssrc, const float* __restrict__ sdst,
                         const float* __restrict__ hv, const float* __restrict__ resid,
                         const float* __restrict__ bng, const float* __restrict__ bnb,
                         const float* __restrict__ bnm, const float* __restrict__ bnv,
                         float* __restrict__ out, int n){
  int node = blockIdx.x * 4 + (threadIdx.x >> 6);
  if (node >= n) return;
  int lane = threadIdx.x & 63;
  int s = rowptr[node], e = rowptr[node + 1];
  float sq = ssrc[node];
  float mx = -INFINITY;
  for (int j = s + lane; j < e; j += 64){
    float t = leaky(sq + sdst[cols[j]]);
    mx = fmaxf(mx, t);
  }
  mx = wred_max(mx);
  float sum = 0.f;
  for (int j = s + lane; j < e; j += 64){
    float t = leaky(sq + sdst[cols[j]]);
    sum += expf(t - mx);
  }
  sum = wred_sum(sum);
  float inv = 1.f / (sum + 1e-16f);
  float a0 = 0.f, a1 = 0.f;
  for (int j = s; j < e; ++j){
    int c = cols[j];
    float t = leaky(sq + sdst[c]);
    float al = expf(t - mx) * inv;
    a0 += al * hv[c * HID + lane];
    a1 += al * hv[c * HID + 64 + lane];
  }
  int d0 = lane, d1 = lane + 64;
  float v0 = (a0 - bnm[d0]) * rsqrtf(bnv[d0] + BN_EPS) * bng[d0] + bnb[d0];
  float v1 = (a1 - bnm[d1]) * rsqrtf(bnv[d1] + BN_EPS) * bng[d1] + bnb[d1];
  if (resid){ v0 += resid[node * HID + d0]; v1 += resid[node * HID + d1]; }
  out[node * HID + d0] = leaky(v0);
  out[node * HID + d1] = leaky(v1);
}

// ---------------- multi-head aggregation + BN + leaky ----------------
__global__ void k_agg_mh(const int* __restrict__ rowptr, const int* __restrict__ cols,
                         const float* __restrict__ ssrc, const float* __restrict__ sdst,
                         const float* __restrict__ hv,
                         const float* __restrict__ bng, const float* __restrict__ bnb,
                         const float* __restrict__ bnm, const float* __restrict__ bnv,
                         float* __restrict__ out, int n){
  int node = blockIdx.x * 4 + (threadIdx.x >> 6);
  if (node >= n) return;
  int lane = threadIdx.x & 63;
  int s = rowptr[node], e = rowptr[node + 1];
  const float4 sq = *(const float4*)&ssrc[node * 4];
  float m0 = -INFINITY, m1 = -INFINITY, m2 = -INFINITY, m3 = -INFINITY;
  for (int j = s + lane; j < e; j += 64){
    int c = cols[j];
    float4 kd = *(const float4*)&sdst[c * 4];
    m0 = fmaxf(m0, leaky(sq.x + kd.x));
    m1 = fmaxf(m1, leaky(sq.y + kd.y));
    m2 = fmaxf(m2, leaky(sq.z + kd.z));
    m3 = fmaxf(m3, leaky(sq.w + kd.w));
  }
  m0 = wred_max(m0); m1 = wred_max(m1); m2 = wred_max(m2); m3 = wred_max(m3);
  float s0 = 0.f, s1 = 0.f, s2 = 0.f, s3 = 0.f;
  for (int j = s + lane; j < e; j += 64){
    int c = cols[j];
    float4 kd = *(const float4*)&sdst[c * 4];
    s0 += expf(leaky(sq.x + kd.x) - m0);
    s1 += expf(leaky(sq.y + kd.y) - m1);
    s2 += expf(leaky(sq.z + kd.z) - m2);
    s3 += expf(leaky(sq.w + kd.w) - m3);
  }
  s0 = wred_sum(s0); s1 = wred_sum(s1); s2 = wred_sum(s2); s3 = wred_sum(s3);
  float i0 = 1.f / (s0 + 1e-16f), i1 = 1.f / (s1 + 1e-16f);
  float i2 = 1.f / (s2 + 1e-16f), i3 = 1.f / (s3 + 1e-16f);
  int hA = lane >> 5;  // head for dim `lane` (0 or 1); dim lane+64 -> head hA+2
  float sqA = hA ? sq.y : sq.x,  sqB = hA ? sq.w : sq.z;
  float mA  = hA ? m1 : m0,      mB  = hA ? m3 : m2;
  float iA  = hA ? i1 : i0,      iB  = hA ? i3 : i2;
  float a0 = 0.f, a1 = 0.f;
  for (int j = s; j < e; ++j){
    int c = cols[j];
    float4 kd = *(const float4*)&sdst[c * 4];
    float kA = hA ? kd.y : kd.x, kB = hA ? kd.w : kd.z;
    float alA = expf(leaky(sqA + kA) - mA) * iA;
    float alB = expf(leaky(sqB + kB) - mB) * iB;
    a0 += alA * hv[c * HID + lane];
    a1 += alB * hv[c * HID + 64 + lane];
  }
  int d0 = lane, d1 = lane + 64;
  float v0 = (a0 - bnm[d0]) * rsqrtf(bnv[d0] + BN_EPS) * bng[d0] + bnb[d0];
  float v1 = (a1 - bnm[d1]) * rsqrtf(bnv[d1] + BN_EPS) * bng[d1] + bnb[d1];
  out[node * HID + d0] = leaky(v0);
  out[node * HID + d1] = leaky(v1);
}

// ---------------- output head: out = x[:,15:18] + o1@Wo2 + bo2 ----------------
__global__ void k_out(const float* __restrict__ o1, const float* __restrict__ Wo2,
                      const float* __restrict__ bo2, const float* __restrict__ x,
                      float* __restrict__ out, int n){
  int node = blockIdx.x * 4 + (threadIdx.x >> 6);
  if (node >= n) return;
  int lane = threadIdx.x & 63;
  float a = o1[node * HID + lane], b = o1[node * HID + 64 + lane];
  float p0 = a * Wo2[lane * 3 + 0] + b * Wo2[(lane + 64) * 3 + 0];
  float p1 = a * Wo2[lane * 3 + 1] + b * Wo2[(lane + 64) * 3 + 1];
  float p2 = a * Wo2[lane * 3 + 2] + b * Wo2[(lane + 64) * 3 + 2];
  p0 = wred_sum(p0); p1 = wred_sum(p1); p2 = wred_sum(p2);
  if (lane == 0){
    out[node * 3 + 0] = x[node * DIN + 15] + p0 + bo2[0];
    out[node * 3 + 1] = x[node * DIN + 16] + p1 + bo2[1];
    out[node * 3 + 2] = x[node * DIN + 17] + p2 + bo2[2];
  }
}

extern "C" void kernel_launch(void* const* d_in, const int* in_sizes, int n_in,
                              void* d_out, int out_size, void* d_ws, size_t ws_size,
                              hipStream_t stream){
  const float* x       = (const float*)d_in[0];
  const int*   ei      = (const int*)  d_in[1];
  const float* W_in    = (const float*)d_in[2];
  const float* b_in    = (const float*)d_in[3];
  const float* W_agg   = (const float*)d_in[4];
  const float* b_agg   = (const float*)d_in[5];
  const float* sh_Wv   = (const float*)d_in[6];
  const float* sh_b    = (const float*)d_in[7];
  const float* sh_asrc = (const float*)d_in[8];
  const float* sh_adst = (const float*)d_in[9];
  const float* mh_Wv   = (const float*)d_in[10];
  const float* mh_b    = (const float*)d_in[11];
  const float* mh_asrc = (const float*)d_in[12];
  const float* mh_adst = (const float*)d_in[13];
  const float* bn_g    = (const float*)d_in[14];
  const float* bn_bt   = (const float*)d_in[15];
  const float* bn_m    = (const float*)d_in[16];
  const float* bn_v    = (const float*)d_in[17];
  const float* W_o1    = (const float*)d_in[18];
  const float* b_o1    = (const float*)d_in[19];
  const float* W_o2    = (const float*)d_in[20];
  const float* b_o2    = (const float*)d_in[21];
  float* out = (float*)d_out;

  const int N = in_sizes[0] / DIN;
  const int E = in_sizes[1] / 2;
  const int* row = ei;
  const int* col = ei + E;

  char* w = (char*)d_ws;
  size_t off = 0;
  auto alloc = [&](size_t bytes) -> void* {
    void* p = w + off;
    off = (off + bytes + 255) & ~(size_t)255;
    return p;
  };
  int*   tmp    = (int*)  alloc((size_t)N * 4);
  int*   rowptr = (int*)  alloc((size_t)(N + 1) * 4);
  int*   cols_s = (int*)  alloc((size_t)E * 4);
  float* nmean  = (float*)alloc((size_t)N * DIN * 4);
  float* ssrc   = (float*)alloc((size_t)N * 4 * 4);
  float* sdst   = (float*)alloc((size_t)N * 4 * 4);
  float* Wcat   = (float*)alloc((size_t)HID * HID * 4);
  float* buf0   = (float*)alloc((size_t)N * HID * 4);
  float* buf1   = (float*)alloc((size_t)N * HID * 4);
  float* buf2   = (float*)alloc((size_t)N * HID * 4);

  const int eb = (E + 255) / 256;
  const int nb4 = (N + 3) / 4;
  const int gemmb = (N + 15) / 16;

  // CSR build
  hipMemsetAsync(tmp, 0, (size_t)N * 4, stream);
  k_deg<<<eb, 256, 0, stream>>>(row, tmp, E);
  k_scan<<<1, 1024, 0, stream>>>(tmp, rowptr, N);
  hipMemsetAsync(tmp, 0, (size_t)N * 4, stream);
  k_fill<<<eb, 256, 0, stream>>>(row, col, rowptr, tmp, cols_s, E);

  // neighbor mean + input projection -> buf0 (= x0 = h)
  k_nmean<<<nb4, 256, 0, stream>>>(x, rowptr, cols_s, nmean, N);
  k_h_in<<<(N * HID + 255) / 256, 256, 0, stream>>>(x, nmean, W_in, b_in, W_agg, b_agg, buf0, N);

  // layer 0: single-head (params [0]), residual = x0(buf0), bn[0] -> buf1
  k_gemm128<<<gemmb, 128, 0, stream>>>(buf0, sh_Wv, sh_b, buf2, N, 0);
  k_scores_sh<<<nb4, 256, 0, stream>>>(buf0, sh_asrc, sh_adst, ssrc, sdst, N);
  k_agg_sh<<<nb4, 256, 0, stream>>>(rowptr, cols_s, ssrc, sdst, buf2, buf0,
                                    bn_g, bn_bt, bn_m, bn_v, buf1, N);

  // layer 1: multi-head, bn[1], no residual -> buf0
  k_rearr<<<(HID * HID + 255) / 256, 256, 0, stream>>>(mh_Wv, Wcat);
  k_gemm128<<<gemmb, 128, 0, stream>>>(buf1, Wcat, mh_b, buf2, N, 0);
  k_scores_mh<<<nb4, 256, 0, stream>>>(buf1, mh_asrc, mh_adst, ssrc, sdst, N);
  k_agg_mh<<<nb4, 256, 0, stream>>>(rowptr, cols_s, ssrc, sdst, buf2,
                                    bn_g + HID, bn_bt + HID, bn_m + HID, bn_v + HID, buf0, N);

  // layer 2: single-head (params [1]), residual = buf0, bn[2] -> buf1
  k_gemm128<<<gemmb, 128, 0, stream>>>(buf0, sh_Wv + HID * HID, sh_b + HID, buf2, N, 0);
  k_scores_sh<<<nb4, 256, 0, stream>>>(buf0, sh_asrc + HID, sh_adst + HID, ssrc, sdst, N);
  k_agg_sh<<<nb4, 256, 0, stream>>>(rowptr, cols_s, ssrc, sdst, buf2, buf0,
                                    bn_g + 2 * HID, bn_bt + 2 * HID, bn_m + 2 * HID, bn_v + 2 * HID,
                                    buf1, N);

  // output head
  k_gemm128<<<gemmb, 128, 0, stream>>>(buf1, W_o1, b_o1, buf2, N, 1);
  k_out<<<nb4, 256, 0, stream>>>(buf2, W_o2, b_o2, x, out, N);
}

// Round 2
// 733.411 us; speedup vs baseline: 1.1664x; 1.1664x over previous
//
#include <hip/hip_runtime.h>
#include <math.h>

#define DIN 18
#define HID 128
#define NEGS 0.2f
#define BN_EPS 1e-5f

__device__ __forceinline__ float leaky(float x){ return x >= 0.f ? x : NEGS * x; }

__device__ __forceinline__ float wred_sum(float v){
  #pragma unroll
  for (int off = 32; off; off >>= 1) v += __shfl_xor(v, off);
  return v;
}
__device__ __forceinline__ float wred_max(float v){
  #pragma unroll
  for (int off = 32; off; off >>= 1) v = fmaxf(v, __shfl_xor(v, off));
  return v;
}

// ---------------- CSR build ----------------
__global__ void k_deg(const int* __restrict__ row, int* __restrict__ deg, int E){
  int i = blockIdx.x * blockDim.x + threadIdx.x;
  if (i < E) atomicAdd(&deg[row[i]], 1);
}

__global__ void k_scan(const int* __restrict__ deg, int* __restrict__ rowptr, int n){
  __shared__ int buf[1024];
  __shared__ int s_carry;
  int tid = threadIdx.x;
  if (tid == 0){ s_carry = 0; rowptr[0] = 0; }
  __syncthreads();
  for (int base = 0; base < n; base += 1024){
    int i = base + tid;
    int v = (i < n) ? deg[i] : 0;
    buf[tid] = v;
    __syncthreads();
    #pragma unroll
    for (int off = 1; off < 1024; off <<= 1){
      int t = (tid >= off) ? buf[tid - off] : 0;
      __syncthreads();
      buf[tid] += t;
      __syncthreads();
    }
    int incl = buf[tid] + s_carry;
    if (i < n) rowptr[i + 1] = incl;
    __syncthreads();
    if (tid == 0) s_carry += buf[1023];
    __syncthreads();
  }
}

__global__ void k_fill(const int* __restrict__ row, const int* __restrict__ col,
                       const int* __restrict__ rowptr, int* __restrict__ cursor,
                       int* __restrict__ cols_s, int E){
  int i = blockIdx.x * blockDim.x + threadIdx.x;
  if (i < E){
    int r = row[i];
    int p = atomicAdd(&cursor[r], 1);
    cols_s[rowptr[r] + p] = col[i];
  }
}

// ---------------- neighbor mean (chunked cols prefetch + shfl broadcast) ----------------
__global__ void k_nmean(const float* __restrict__ x, const int* __restrict__ rowptr,
                        const int* __restrict__ cols, float* __restrict__ nmean, int n){
  int node = blockIdx.x * 4 + (threadIdx.x >> 6);
  if (node >= n) return;
  int lane = threadIdx.x & 63;
  int s = rowptr[node], e = rowptr[node + 1];
  float acc = 0.f;
  for (int j0 = s; j0 < e; j0 += 64){
    int len = min(64, e - j0);
    int cv = (lane < len) ? cols[j0 + lane] : 0;
    for (int k = 0; k < len; ++k){
      int c = __shfl(cv, k);
      if (lane < DIN) acc += x[c * DIN + lane];
    }
  }
  if (lane < DIN){
    float d = (float)(e - s);
    nmean[node * DIN + lane] = acc / (d + 1e-8f);
  }
}

// ---------------- input projection: h = x@Win + nmean@Wagg + biases ----------------
__global__ void k_h_in(const float* __restrict__ x, const float* __restrict__ nmean,
                       const float* __restrict__ Win, const float* __restrict__ bin,
                       const float* __restrict__ Wagg, const float* __restrict__ bagg,
                       float* __restrict__ out, int n){
  int i = blockIdx.x * blockDim.x + threadIdx.x;
  if (i >= n * HID) return;
  int node = i >> 7, c = i & 127;
  float acc = bin[c] + bagg[c];
  const float* xr = &x[node * DIN];
  const float* nr = &nmean[node * DIN];
  #pragma unroll
  for (int d = 0; d < DIN; ++d){
    acc += xr[d] * Win[d * HID + c] + nr[d] * Wagg[d * HID + c];
  }
  out[i] = acc;
}

// ---------------- generic 128x128 GEMM, 16 nodes/block ----------------
__global__ void k_gemm128(const float* __restrict__ src, const float* __restrict__ W,
                          const float* __restrict__ bias, float* __restrict__ dst,
                          int n, int mode){
  __shared__ float hs[16][HID];
  int tid = threadIdx.x;
  int base = blockIdx.x * 16;
  #pragma unroll
  for (int k = 0; k < 16; ++k){
    int nd = base + k;
    hs[k][tid] = (nd < n) ? src[nd * HID + tid] : 0.f;
  }
  __syncthreads();
  float acc[16];
  #pragma unroll
  for (int k = 0; k < 16; ++k) acc[k] = 0.f;
  for (int d = 0; d < HID; ++d){
    float w = W[d * HID + tid];
    #pragma unroll
    for (int k = 0; k < 16; ++k) acc[k] += hs[k][d] * w;
  }
  float b = bias[tid];
  #pragma unroll
  for (int k = 0; k < 16; ++k){
    int nd = base + k;
    if (nd < n){
      float v = acc[k] + b;
      if (mode == 1) v = leaky(v);
      dst[nd * HID + tid] = v;
    }
  }
}

// ---------------- rearrange mh_Wv [4][128][32] -> Wcat [128][128] ----------------
__global__ void k_rearr(const float* __restrict__ mhWv, float* __restrict__ Wcat){
  int i = blockIdx.x * blockDim.x + threadIdx.x;
  if (i >= HID * HID) return;
  int d = i >> 7, c = i & 127;
  Wcat[i] = mhWv[((c >> 5) * HID + d) * 32 + (c & 31)];
}

// ---------------- single-head scores ----------------
__global__ void k_scores_sh(const float* __restrict__ h, const float* __restrict__ asrc,
                            const float* __restrict__ adst,
                            float* __restrict__ ssrc, float* __restrict__ sdst, int n){
  int node = blockIdx.x * 4 + (threadIdx.x >> 6);
  if (node >= n) return;
  int lane = threadIdx.x & 63;
  float h0 = h[node * HID + lane], h1 = h[node * HID + 64 + lane];
  float ps = h0 * asrc[lane] + h1 * asrc[64 + lane];
  float pd = h0 * adst[lane] + h1 * adst[64 + lane];
  ps = wred_sum(ps);
  pd = wred_sum(pd);
  if (lane == 0){ ssrc[node] = ps; sdst[node] = pd; }
}

// ---------------- multi-head scores ----------------
__global__ void k_scores_mh(const float* __restrict__ h, const float* __restrict__ asrc,
                            const float* __restrict__ adst,
                            float* __restrict__ ssrc, float* __restrict__ sdst, int n){
  int node = blockIdx.x * 4 + (threadIdx.x >> 6);
  if (node >= n) return;
  int lane = threadIdx.x & 63;
  float h0 = h[node * HID + lane], h1 = h[node * HID + 64 + lane];
  #pragma unroll
  for (int hd = 0; hd < 4; ++hd){
    float ps = h0 * asrc[hd * HID + lane] + h1 * asrc[hd * HID + 64 + lane];
    float pd = h0 * adst[hd * HID + lane] + h1 * adst[hd * HID + 64 + lane];
    ps = wred_sum(ps);
    pd = wred_sum(pd);
    if (lane == 0){ ssrc[node * 4 + hd] = ps; sdst[node * 4 + hd] = pd; }
  }
}

// ---------------- single-head aggregation: one-pass online softmax ----------------
__global__ void k_agg_sh(const int* __restrict__ rowptr, const int* __restrict__ cols,
                         const float* __restrict__ ssrc, const float* __restrict__ sdst,
                         const float* __restrict__ hv, const float* __restrict__ resid,
                         const float* __restrict__ bng, const float* __restrict__ bnb,
                         const float* __restrict__ bnm, const float* __restrict__ bnv,
                         float* __restrict__ out, int n){
  int node = blockIdx.x * 4 + (threadIdx.x >> 6);
  if (node >= n) return;
  int lane = threadIdx.x & 63;
  int s = rowptr[node], e = rowptr[node + 1];
  float sq = ssrc[node];
  float m_run = -INFINITY, ssum = 0.f, a0 = 0.f, a1 = 0.f;
  for (int j0 = s; j0 < e; j0 += 64){
    int len = min(64, e - j0);
    int cv = (lane < len) ? cols[j0 + lane] : 0;
    float tv = (lane < len) ? leaky(sq + sdst[cv]) : -INFINITY;
    float cm = wred_max(tv);
    float m_new = fmaxf(m_run, cm);
    float sc = __expf(m_run - m_new);   // first chunk: exp(-inf)=0
    ssum *= sc; a0 *= sc; a1 *= sc;
    m_run = m_new;
    float ex = __expf(tv - m_run);      // inactive lanes: exp(-inf)=0
    ssum += wred_sum(ex);
    for (int k = 0; k < len; ++k){
      float al = __shfl(ex, k);
      int c = __shfl(cv, k);
      a0 += al * hv[c * HID + lane];
      a1 += al * hv[c * HID + 64 + lane];
    }
  }
  float inv = 1.f / (ssum + 1e-16f);
  a0 *= inv; a1 *= inv;
  int d0 = lane, d1 = lane + 64;
  float v0 = (a0 - bnm[d0]) * rsqrtf(bnv[d0] + BN_EPS) * bng[d0] + bnb[d0];
  float v1 = (a1 - bnm[d1]) * rsqrtf(bnv[d1] + BN_EPS) * bng[d1] + bnb[d1];
  if (resid){ v0 += resid[node * HID + d0]; v1 += resid[node * HID + d1]; }
  out[node * HID + d0] = leaky(v0);
  out[node * HID + d1] = leaky(v1);
}

// ---------------- multi-head aggregation: one-pass online softmax ----------------
__global__ void k_agg_mh(const int* __restrict__ rowptr, const int* __restrict__ cols,
                         const float* __restrict__ ssrc, const float* __restrict__ sdst,
                         const float* __restrict__ hv,
                         const float* __restrict__ bng, const float* __restrict__ bnb,
                         const float* __restrict__ bnm, const float* __restrict__ bnv,
                         float* __restrict__ out, int n){
  int node = blockIdx.x * 4 + (threadIdx.x >> 6);
  if (node >= n) return;
  int lane = threadIdx.x & 63;
  int s = rowptr[node], e = rowptr[node + 1];
  const float4 sq = *(const float4*)&ssrc[node * 4];
  int hA = lane >> 5;  // head for dim `lane`; dim lane+64 -> head hA+2
  float m0 = -INFINITY, m1 = -INFINITY, m2 = -INFINITY, m3 = -INFINITY;
  float s0 = 0.f, s1 = 0.f, s2 = 0.f, s3 = 0.f;
  float a0 = 0.f, a1 = 0.f;
  for (int j0 = s; j0 < e; j0 += 64){
    int len = min(64, e - j0);
    int cv = (lane < len) ? cols[j0 + lane] : 0;
    float t0, t1, t2, t3;
    if (lane < len){
      float4 kd = *(const float4*)&sdst[cv * 4];
      t0 = leaky(sq.x + kd.x); t1 = leaky(sq.y + kd.y);
      t2 = leaky(sq.z + kd.z); t3 = leaky(sq.w + kd.w);
    } else {
      t0 = t1 = t2 = t3 = -INFINITY;
    }
    float n0 = fmaxf(m0, wred_max(t0));
    float n1 = fmaxf(m1, wred_max(t1));
    float n2 = fmaxf(m2, wred_max(t2));
    float n3 = fmaxf(m3, wred_max(t3));
    float c0 = __expf(m0 - n0), c1 = __expf(m1 - n1);
    float c2 = __expf(m2 - n2), c3 = __expf(m3 - n3);
    s0 *= c0; s1 *= c1; s2 *= c2; s3 *= c3;
    a0 *= hA ? c1 : c0;
    a1 *= hA ? c3 : c2;
    m0 = n0; m1 = n1; m2 = n2; m3 = n3;
    float e0 = __expf(t0 - m0), e1 = __expf(t1 - m1);
    float e2 = __expf(t2 - m2), e3 = __expf(t3 - m3);
    s0 += wred_sum(e0); s1 += wred_sum(e1);
    s2 += wred_sum(e2); s3 += wred_sum(e3);
    float exA = hA ? e1 : e0;
    float exB = hA ? e3 : e2;
    for (int k = 0; k < len; ++k){
      // need edge-k's ex for this lane's heads: broadcast both candidates
      float bx0 = __shfl(e0, k), bx1 = __shfl(e1, k);
      float bx2 = __shfl(e2, k), bx3 = __shfl(e3, k);
      int c = __shfl(cv, k);
      float alA = hA ? bx1 : bx0;
      float alB = hA ? bx3 : bx2;
      a0 += alA * hv[c * HID + lane];
      a1 += alB * hv[c * HID + 64 + lane];
    }
    (void)exA; (void)exB;
  }
  float i0 = 1.f / (s0 + 1e-16f), i1 = 1.f / (s1 + 1e-16f);
  float i2 = 1.f / (s2 + 1e-16f), i3 = 1.f / (s3 + 1e-16f);
  a0 *= hA ? i1 : i0;
  a1 *= hA ? i3 : i2;
  int d0 = lane, d1 = lane + 64;
  float v0 = (a0 - bnm[d0]) * rsqrtf(bnv[d0] + BN_EPS) * bng[d0] + bnb[d0];
  float v1 = (a1 - bnm[d1]) * rsqrtf(bnv[d1] + BN_EPS) * bng[d1] + bnb[d1];
  out[node * HID + d0] = leaky(v0);
  out[node * HID + d1] = leaky(v1);
}

// ---------------- output head: out = x[:,15:18] + o1@Wo2 + bo2 ----------------
__global__ void k_out(const float* __restrict__ o1, const float* __restrict__ Wo2,
                      const float* __restrict__ bo2, const float* __restrict__ x,
                      float* __restrict__ out, int n){
  int node = blockIdx.x * 4 + (threadIdx.x >> 6);
  if (node >= n) return;
  int lane = threadIdx.x & 63;
  float a = o1[node * HID + lane], b = o1[node * HID + 64 + lane];
  float p0 = a * Wo2[lane * 3 + 0] + b * Wo2[(lane + 64) * 3 + 0];
  float p1 = a * Wo2[lane * 3 + 1] + b * Wo2[(lane + 64) * 3 + 1];
  float p2 = a * Wo2[lane * 3 + 2] + b * Wo2[(lane + 64) * 3 + 2];
  p0 = wred_sum(p0); p1 = wred_sum(p1); p2 = wred_sum(p2);
  if (lane == 0){
    out[node * 3 + 0] = x[node * DIN + 15] + p0 + bo2[0];
    out[node * 3 + 1] = x[node * DIN + 16] + p1 + bo2[1];
    out[node * 3 + 2] = x[node * DIN + 17] + p2 + bo2[2];
  }
}

extern "C" void kernel_launch(void* const* d_in, const int* in_sizes, int n_in,
                              void* d_out, int out_size, void* d_ws, size_t ws_size,
                              hipStream_t stream){
  const float* x       = (const float*)d_in[0];
  const int*   ei      = (const int*)  d_in[1];
  const float* W_in    = (const float*)d_in[2];
  const float* b_in    = (const float*)d_in[3];
  const float* W_agg   = (const float*)d_in[4];
  const float* b_agg   = (const float*)d_in[5];
  const float* sh_Wv   = (const float*)d_in[6];
  const float* sh_b    = (const float*)d_in[7];
  const float* sh_asrc = (const float*)d_in[8];
  const float* sh_adst = (const float*)d_in[9];
  const float* mh_Wv   = (const float*)d_in[10];
  const float* mh_b    = (const float*)d_in[11];
  const float* mh_asrc = (const float*)d_in[12];
  const float* mh_adst = (const float*)d_in[13];
  const float* bn_g    = (const float*)d_in[14];
  const float* bn_bt   = (const float*)d_in[15];
  const float* bn_m    = (const float*)d_in[16];
  const float* bn_v    = (const float*)d_in[17];
  const float* W_o1    = (const float*)d_in[18];
  const float* b_o1    = (const float*)d_in[19];
  const float* W_o2    = (const float*)d_in[20];
  const float* b_o2    = (const float*)d_in[21];
  float* out = (float*)d_out;

  const int N = in_sizes[0] / DIN;
  const int E = in_sizes[1] / 2;
  const int* row = ei;
  const int* col = ei + E;

  char* w = (char*)d_ws;
  size_t off = 0;
  auto alloc = [&](size_t bytes) -> void* {
    void* p = w + off;
    off = (off + bytes + 255) & ~(size_t)255;
    return p;
  };
  int*   tmp    = (int*)  alloc((size_t)N * 4);
  int*   rowptr = (int*)  alloc((size_t)(N + 1) * 4);
  int*   cols_s = (int*)  alloc((size_t)E * 4);
  float* nmean  = (float*)alloc((size_t)N * DIN * 4);
  float* ssrc   = (float*)alloc((size_t)N * 4 * 4);
  float* sdst   = (float*)alloc((size_t)N * 4 * 4);
  float* Wcat   = (float*)alloc((size_t)HID * HID * 4);
  float* buf0   = (float*)alloc((size_t)N * HID * 4);
  float* buf1   = (float*)alloc((size_t)N * HID * 4);
  float* buf2   = (float*)alloc((size_t)N * HID * 4);

  const int eb = (E + 255) / 256;
  const int nb4 = (N + 3) / 4;
  const int gemmb = (N + 15) / 16;

  // CSR build
  hipMemsetAsync(tmp, 0, (size_t)N * 4, stream);
  k_deg<<<eb, 256, 0, stream>>>(row, tmp, E);
  k_scan<<<1, 1024, 0, stream>>>(tmp, rowptr, N);
  hipMemsetAsync(tmp, 0, (size_t)N * 4, stream);
  k_fill<<<eb, 256, 0, stream>>>(row, col, rowptr, tmp, cols_s, E);

  // neighbor mean + input projection -> buf0 (= x0 = h)
  k_nmean<<<nb4, 256, 0, stream>>>(x, rowptr, cols_s, nmean, N);
  k_h_in<<<(N * HID + 255) / 256, 256, 0, stream>>>(x, nmean, W_in, b_in, W_agg, b_agg, buf0, N);

  // layer 0: single-head (params [0]), residual = x0(buf0), bn[0] -> buf1
  k_gemm128<<<gemmb, 128, 0, stream>>>(buf0, sh_Wv, sh_b, buf2, N, 0);
  k_scores_sh<<<nb4, 256, 0, stream>>>(buf0, sh_asrc, sh_adst, ssrc, sdst, N);
  k_agg_sh<<<nb4, 256, 0, stream>>>(rowptr, cols_s, ssrc, sdst, buf2, buf0,
                                    bn_g, bn_bt, bn_m, bn_v, buf1, N);

  // layer 1: multi-head, bn[1], no residual -> buf0
  k_rearr<<<(HID * HID + 255) / 256, 256, 0, stream>>>(mh_Wv, Wcat);
  k_gemm128<<<gemmb, 128, 0, stream>>>(buf1, Wcat, mh_b, buf2, N, 0);
  k_scores_mh<<<nb4, 256, 0, stream>>>(buf1, mh_asrc, mh_adst, ssrc, sdst, N);
  k_agg_mh<<<nb4, 256, 0, stream>>>(rowptr, cols_s, ssrc, sdst, buf2,
                                    bn_g + HID, bn_bt + HID, bn_m + HID, bn_v + HID, buf0, N);

  // layer 2: single-head (params [1]), residual = buf0, bn[2] -> buf1
  k_gemm128<<<gemmb, 128, 0, stream>>>(buf0, sh_Wv + HID * HID, sh_b + HID, buf2, N, 0);
  k_scores_sh<<<nb4, 256, 0, stream>>>(buf0, sh_asrc + HID, sh_adst + HID, ssrc, sdst, N);
  k_agg_sh<<<nb4, 256, 0, stream>>>(rowptr, cols_s, ssrc, sdst, buf2, buf0,
                                    bn_g + 2 * HID, bn_bt + 2 * HID, bn_m + 2 * HID, bn_v + 2 * HID,
                                    buf1, N);

  // output head
  k_gemm128<<<gemmb, 128, 0, stream>>>(buf1, W_o1, b_o1, buf2, N, 1);
  k_out<<<nb4, 256, 0, stream>>>(buf2, W_o2, b_o2, x, out, N);
}

// Round 3
// 656.543 us; speedup vs baseline: 1.3030x; 1.1171x over previous
//
#include <hip/hip_runtime.h>
#include <math.h>

#define DIN 18
#define HID 128
#define NEGS 0.2f
#define BN_EPS 1e-5f
#define SCHUNK 2048   // elements per scan block (256 thr x 8)

__device__ __forceinline__ float leaky(float x){ return x >= 0.f ? x : NEGS * x; }

__device__ __forceinline__ float wred_sum(float v){
  #pragma unroll
  for (int off = 32; off; off >>= 1) v += __shfl_xor(v, off);
  return v;
}
__device__ __forceinline__ float wred_max(float v){
  #pragma unroll
  for (int off = 32; off; off >>= 1) v = fmaxf(v, __shfl_xor(v, off));
  return v;
}

// ---------------- CSR build ----------------
__global__ void k_deg(const int* __restrict__ row, int* __restrict__ deg, int E){
  int i = blockIdx.x * blockDim.x + threadIdx.x;
  if (i < E) atomicAdd(&deg[row[i]], 1);
}

// phase 1: per-block chunk sums
__global__ void k_scan1(const int* __restrict__ deg, int* __restrict__ bsum, int n){
  __shared__ int wtot[4];
  int tid = threadIdx.x, lane = tid & 63, wid = tid >> 6;
  int base = blockIdx.x * SCHUNK + tid * 8;
  int acc = 0;
  #pragma unroll
  for (int j = 0; j < 8; ++j){
    int i = base + j;
    if (i < n) acc += deg[i];
  }
  #pragma unroll
  for (int off = 32; off; off >>= 1) acc += __shfl_xor(acc, off);
  if (lane == 0) wtot[wid] = acc;
  __syncthreads();
  if (tid == 0) bsum[blockIdx.x] = wtot[0] + wtot[1] + wtot[2] + wtot[3];
}

// phase 2: single-wave inclusive scan over block sums
__global__ void k_scan2(int* __restrict__ bsum, int nb){
  int lane = threadIdx.x;
  int carry = 0;
  for (int base = 0; base < nb; base += 64){
    int i = base + lane;
    int v = (i < nb) ? bsum[i] : 0;
    #pragma unroll
    for (int off = 1; off < 64; off <<= 1){
      int u = __shfl_up(v, off);
      if (lane >= off) v += u;
    }
    if (i < nb) bsum[i] = v + carry;
    carry += __shfl(v, 63);
  }
}

// phase 3: per-block local scan + global offset -> rowptr
__global__ void k_scan3(const int* __restrict__ deg, const int* __restrict__ bsum,
                        int* __restrict__ rowptr, int n){
  __shared__ int wtot[4];
  int tid = threadIdx.x, lane = tid & 63, wid = tid >> 6;
  int base = blockIdx.x * SCHUNK + tid * 8;
  int l[8];
  int acc = 0;
  #pragma unroll
  for (int j = 0; j < 8; ++j){
    int i = base + j;
    acc += (i < n) ? deg[i] : 0;
    l[j] = acc;
  }
  // inclusive wave scan of thread totals
  int v = acc;
  #pragma unroll
  for (int off = 1; off < 64; off <<= 1){
    int u = __shfl_up(v, off);
    if (lane >= off) v += u;
  }
  if (lane == 63) wtot[wid] = v;
  __syncthreads();
  int woff = 0;
  for (int w = 0; w < wid; ++w) woff += wtot[w];
  int boff = (blockIdx.x == 0) ? 0 : bsum[blockIdx.x - 1];
  int tpre = boff + woff + (v - acc);   // exclusive prefix before this thread
  #pragma unroll
  for (int j = 0; j < 8; ++j){
    int i = base + j;
    if (i < n) rowptr[i + 1] = tpre + l[j];
  }
  if (blockIdx.x == 0 && tid == 0) rowptr[0] = 0;
}

__global__ void k_fill(const int* __restrict__ row, const int* __restrict__ col,
                       const int* __restrict__ rowptr, int* __restrict__ cursor,
                       int* __restrict__ cols_s, int E){
  int i = blockIdx.x * blockDim.x + threadIdx.x;
  if (i < E){
    int r = row[i];
    int p = atomicAdd(&cursor[r], 1);
    cols_s[rowptr[r] + p] = col[i];
  }
}

// ---------------- neighbor mean (chunked cols prefetch + shfl broadcast) ----------------
__global__ void k_nmean(const float* __restrict__ x, const int* __restrict__ rowptr,
                        const int* __restrict__ cols, float* __restrict__ nmean, int n){
  int node = blockIdx.x * 4 + (threadIdx.x >> 6);
  if (node >= n) return;
  int lane = threadIdx.x & 63;
  int s = rowptr[node], e = rowptr[node + 1];
  float acc = 0.f;
  for (int j0 = s; j0 < e; j0 += 64){
    int len = min(64, e - j0);
    int cv = (lane < len) ? cols[j0 + lane] : 0;
    for (int k = 0; k < len; ++k){
      int c = __shfl(cv, k);
      if (lane < DIN) acc += x[c * DIN + lane];
    }
  }
  if (lane < DIN){
    float d = (float)(e - s);
    nmean[node * DIN + lane] = acc / (d + 1e-8f);
  }
}

// ---------------- input projection: h = x@Win + nmean@Wagg + biases ----------------
__global__ void k_h_in(const float* __restrict__ x, const float* __restrict__ nmean,
                       const float* __restrict__ Win, const float* __restrict__ bin,
                       const float* __restrict__ Wagg, const float* __restrict__ bagg,
                       float* __restrict__ out, int n){
  int i = blockIdx.x * blockDim.x + threadIdx.x;
  if (i >= n * HID) return;
  int node = i >> 7, c = i & 127;
  float acc = bin[c] + bagg[c];
  const float* xr = &x[node * DIN];
  const float* nr = &nmean[node * DIN];
  #pragma unroll
  for (int d = 0; d < DIN; ++d){
    acc += xr[d] * Win[d * HID + c] + nr[d] * Wagg[d * HID + c];
  }
  out[i] = acc;
}

// ---------------- generic 128x128 GEMM, 16 nodes/block ----------------
__global__ void k_gemm128(const float* __restrict__ src, const float* __restrict__ W,
                          const float* __restrict__ bias, float* __restrict__ dst,
                          int n, int mode){
  __shared__ float hs[16][HID];
  int tid = threadIdx.x;
  int base = blockIdx.x * 16;
  #pragma unroll
  for (int k = 0; k < 16; ++k){
    int nd = base + k;
    hs[k][tid] = (nd < n) ? src[nd * HID + tid] : 0.f;
  }
  __syncthreads();
  float acc[16];
  #pragma unroll
  for (int k = 0; k < 16; ++k) acc[k] = 0.f;
  for (int d = 0; d < HID; ++d){
    float w = W[d * HID + tid];
    #pragma unroll
    for (int k = 0; k < 16; ++k) acc[k] += hs[k][d] * w;
  }
  float b = bias[tid];
  #pragma unroll
  for (int k = 0; k < 16; ++k){
    int nd = base + k;
    if (nd < n){
      float v = acc[k] + b;
      if (mode == 1) v = leaky(v);
      dst[nd * HID + tid] = v;
    }
  }
}

// ---------------- rearrange mh_Wv [4][128][32] -> Wcat [128][128] ----------------
__global__ void k_rearr(const float* __restrict__ mhWv, float* __restrict__ Wcat){
  int i = blockIdx.x * blockDim.x + threadIdx.x;
  if (i >= HID * HID) return;
  int d = i >> 7, c = i & 127;
  Wcat[i] = mhWv[((c >> 5) * HID + d) * 32 + (c & 31)];
}

// ---------------- single-head scores ----------------
__global__ void k_scores_sh(const float* __restrict__ h, const float* __restrict__ asrc,
                            const float* __restrict__ adst,
                            float* __restrict__ ssrc, float* __restrict__ sdst, int n){
  int node = blockIdx.x * 4 + (threadIdx.x >> 6);
  if (node >= n) return;
  int lane = threadIdx.x & 63;
  float h0 = h[node * HID + lane], h1 = h[node * HID + 64 + lane];
  float ps = h0 * asrc[lane] + h1 * asrc[64 + lane];
  float pd = h0 * adst[lane] + h1 * adst[64 + lane];
  ps = wred_sum(ps);
  pd = wred_sum(pd);
  if (lane == 0){ ssrc[node] = ps; sdst[node] = pd; }
}

// ---------------- multi-head scores ----------------
__global__ void k_scores_mh(const float* __restrict__ h, const float* __restrict__ asrc,
                            const float* __restrict__ adst,
                            float* __restrict__ ssrc, float* __restrict__ sdst, int n){
  int node = blockIdx.x * 4 + (threadIdx.x >> 6);
  if (node >= n) return;
  int lane = threadIdx.x & 63;
  float h0 = h[node * HID + lane], h1 = h[node * HID + 64 + lane];
  #pragma unroll
  for (int hd = 0; hd < 4; ++hd){
    float ps = h0 * asrc[hd * HID + lane] + h1 * asrc[hd * HID + 64 + lane];
    float pd = h0 * adst[hd * HID + lane] + h1 * adst[hd * HID + 64 + lane];
    ps = wred_sum(ps);
    pd = wred_sum(pd);
    if (lane == 0){ ssrc[node * 4 + hd] = ps; sdst[node * 4 + hd] = pd; }
  }
}

// ---------------- single-head aggregation: one-pass online softmax ----------------
__global__ void k_agg_sh(const int* __restrict__ rowptr, const int* __restrict__ cols,
                         const float* __restrict__ ssrc, const float* __restrict__ sdst,
                         const float* __restrict__ hv, const float* __restrict__ resid,
                         const float* __restrict__ bng, const float* __restrict__ bnb,
                         const float* __restrict__ bnm, const float* __restrict__ bnv,
                         float* __restrict__ out, int n){
  int node = blockIdx.x * 4 + (threadIdx.x >> 6);
  if (node >= n) return;
  int lane = threadIdx.x & 63;
  int s = rowptr[node], e = rowptr[node + 1];
  float sq = ssrc[node];
  float m_run = -INFINITY, ssum = 0.f, a0 = 0.f, a1 = 0.f;
  for (int j0 = s; j0 < e; j0 += 64){
    int len = min(64, e - j0);
    int cv = (lane < len) ? cols[j0 + lane] : 0;
    float tv = (lane < len) ? leaky(sq + sdst[cv]) : -INFINITY;
    float cm = wred_max(tv);
    float m_new = fmaxf(m_run, cm);
    float sc = __expf(m_run - m_new);   // first chunk: exp(-inf)=0
    ssum *= sc; a0 *= sc; a1 *= sc;
    m_run = m_new;
    float ex = __expf(tv - m_run);      // inactive lanes: exp(-inf)=0
    ssum += wred_sum(ex);
    for (int k = 0; k < len; ++k){
      float al = __shfl(ex, k);
      int c = __shfl(cv, k);
      a0 += al * hv[c * HID + lane];
      a1 += al * hv[c * HID + 64 + lane];
    }
  }
  float inv = 1.f / (ssum + 1e-16f);
  a0 *= inv; a1 *= inv;
  int d0 = lane, d1 = lane + 64;
  float v0 = (a0 - bnm[d0]) * rsqrtf(bnv[d0] + BN_EPS) * bng[d0] + bnb[d0];
  float v1 = (a1 - bnm[d1]) * rsqrtf(bnv[d1] + BN_EPS) * bng[d1] + bnb[d1];
  if (resid){ v0 += resid[node * HID + d0]; v1 += resid[node * HID + d1]; }
  out[node * HID + d0] = leaky(v0);
  out[node * HID + d1] = leaky(v1);
}

// ---------------- multi-head aggregation: one-pass online softmax ----------------
__global__ void k_agg_mh(const int* __restrict__ rowptr, const int* __restrict__ cols,
                         const float* __restrict__ ssrc, const float* __restrict__ sdst,
                         const float* __restrict__ hv,
                         const float* __restrict__ bng, const float* __restrict__ bnb,
                         const float* __restrict__ bnm, const float* __restrict__ bnv,
                         float* __restrict__ out, int n){
  int node = blockIdx.x * 4 + (threadIdx.x >> 6);
  if (node >= n) return;
  int lane = threadIdx.x & 63;
  int s = rowptr[node], e = rowptr[node + 1];
  const float4 sq = *(const float4*)&ssrc[node * 4];
  int hA = lane >> 5;  // head for dim `lane`; dim lane+64 -> head hA+2
  float m0 = -INFINITY, m1 = -INFINITY, m2 = -INFINITY, m3 = -INFINITY;
  float s0 = 0.f, s1 = 0.f, s2 = 0.f, s3 = 0.f;
  float a0 = 0.f, a1 = 0.f;
  for (int j0 = s; j0 < e; j0 += 64){
    int len = min(64, e - j0);
    int cv = (lane < len) ? cols[j0 + lane] : 0;
    float t0, t1, t2, t3;
    if (lane < len){
      float4 kd = *(const float4*)&sdst[cv * 4];
      t0 = leaky(sq.x + kd.x); t1 = leaky(sq.y + kd.y);
      t2 = leaky(sq.z + kd.z); t3 = leaky(sq.w + kd.w);
    } else {
      t0 = t1 = t2 = t3 = -INFINITY;
    }
    float n0 = fmaxf(m0, wred_max(t0));
    float n1 = fmaxf(m1, wred_max(t1));
    float n2 = fmaxf(m2, wred_max(t2));
    float n3 = fmaxf(m3, wred_max(t3));
    float c0 = __expf(m0 - n0), c1 = __expf(m1 - n1);
    float c2 = __expf(m2 - n2), c3 = __expf(m3 - n3);
    s0 *= c0; s1 *= c1; s2 *= c2; s3 *= c3;
    a0 *= hA ? c1 : c0;
    a1 *= hA ? c3 : c2;
    m0 = n0; m1 = n1; m2 = n2; m3 = n3;
    float e0 = __expf(t0 - m0), e1 = __expf(t1 - m1);
    float e2 = __expf(t2 - m2), e3 = __expf(t3 - m3);
    s0 += wred_sum(e0); s1 += wred_sum(e1);
    s2 += wred_sum(e2); s3 += wred_sum(e3);
    for (int k = 0; k < len; ++k){
      float bx0 = __shfl(e0, k), bx1 = __shfl(e1, k);
      float bx2 = __shfl(e2, k), bx3 = __shfl(e3, k);
      int c = __shfl(cv, k);
      float alA = hA ? bx1 : bx0;
      float alB = hA ? bx3 : bx2;
      a0 += alA * hv[c * HID + lane];
      a1 += alB * hv[c * HID + 64 + lane];
    }
  }
  float i0 = 1.f / (s0 + 1e-16f), i1 = 1.f / (s1 + 1e-16f);
  float i2 = 1.f / (s2 + 1e-16f), i3 = 1.f / (s3 + 1e-16f);
  a0 *= hA ? i1 : i0;
  a1 *= hA ? i3 : i2;
  int d0 = lane, d1 = lane + 64;
  float v0 = (a0 - bnm[d0]) * rsqrtf(bnv[d0] + BN_EPS) * bng[d0] + bnb[d0];
  float v1 = (a1 - bnm[d1]) * rsqrtf(bnv[d1] + BN_EPS) * bng[d1] + bnb[d1];
  out[node * HID + d0] = leaky(v0);
  out[node * HID + d1] = leaky(v1);
}

// ---------------- output head: out = x[:,15:18] + o1@Wo2 + bo2 ----------------
__global__ void k_out(const float* __restrict__ o1, const float* __restrict__ Wo2,
                      const float* __restrict__ bo2, const float* __restrict__ x,
                      float* __restrict__ out, int n){
  int node = blockIdx.x * 4 + (threadIdx.x >> 6);
  if (node >= n) return;
  int lane = threadIdx.x & 63;
  float a = o1[node * HID + lane], b = o1[node * HID + 64 + lane];
  float p0 = a * Wo2[lane * 3 + 0] + b * Wo2[(lane + 64) * 3 + 0];
  float p1 = a * Wo2[lane * 3 + 1] + b * Wo2[(lane + 64) * 3 + 1];
  float p2 = a * Wo2[lane * 3 + 2] + b * Wo2[(lane + 64) * 3 + 2];
  p0 = wred_sum(p0); p1 = wred_sum(p1); p2 = wred_sum(p2);
  if (lane == 0){
    out[node * 3 + 0] = x[node * DIN + 15] + p0 + bo2[0];
    out[node * 3 + 1] = x[node * DIN + 16] + p1 + bo2[1];
    out[node * 3 + 2] = x[node * DIN + 17] + p2 + bo2[2];
  }
}

extern "C" void kernel_launch(void* const* d_in, const int* in_sizes, int n_in,
                              void* d_out, int out_size, void* d_ws, size_t ws_size,
                              hipStream_t stream){
  const float* x       = (const float*)d_in[0];
  const int*   ei      = (const int*)  d_in[1];
  const float* W_in    = (const float*)d_in[2];
  const float* b_in    = (const float*)d_in[3];
  const float* W_agg   = (const float*)d_in[4];
  const float* b_agg   = (const float*)d_in[5];
  const float* sh_Wv   = (const float*)d_in[6];
  const float* sh_b    = (const float*)d_in[7];
  const float* sh_asrc = (const float*)d_in[8];
  const float* sh_adst = (const float*)d_in[9];
  const float* mh_Wv   = (const float*)d_in[10];
  const float* mh_b    = (const float*)d_in[11];
  const float* mh_asrc = (const float*)d_in[12];
  const float* mh_adst = (const float*)d_in[13];
  const float* bn_g    = (const float*)d_in[14];
  const float* bn_bt   = (const float*)d_in[15];
  const float* bn_m    = (const float*)d_in[16];
  const float* bn_v    = (const float*)d_in[17];
  const float* W_o1    = (const float*)d_in[18];
  const float* b_o1    = (const float*)d_in[19];
  const float* W_o2    = (const float*)d_in[20];
  const float* b_o2    = (const float*)d_in[21];
  float* out = (float*)d_out;

  const int N = in_sizes[0] / DIN;
  const int E = in_sizes[1] / 2;
  const int* row = ei;
  const int* col = ei + E;

  char* w = (char*)d_ws;
  size_t off = 0;
  auto alloc = [&](size_t bytes) -> void* {
    void* p = w + off;
    off = (off + bytes + 255) & ~(size_t)255;
    return p;
  };
  int*   tmp    = (int*)  alloc((size_t)N * 4);
  int*   rowptr = (int*)  alloc((size_t)(N + 1) * 4);
  int*   cols_s = (int*)  alloc((size_t)E * 4);
  int*   bsum   = (int*)  alloc((size_t)1024 * 4);
  float* nmean  = (float*)alloc((size_t)N * DIN * 4);
  float* ssrc   = (float*)alloc((size_t)N * 4 * 4);
  float* sdst   = (float*)alloc((size_t)N * 4 * 4);
  float* Wcat   = (float*)alloc((size_t)HID * HID * 4);
  float* buf0   = (float*)alloc((size_t)N * HID * 4);
  float* buf1   = (float*)alloc((size_t)N * HID * 4);
  float* buf2   = (float*)alloc((size_t)N * HID * 4);

  const int eb = (E + 255) / 256;
  const int nb4 = (N + 3) / 4;
  const int gemmb = (N + 15) / 16;
  const int nsb = (N + SCHUNK - 1) / SCHUNK;

  // CSR build
  hipMemsetAsync(tmp, 0, (size_t)N * 4, stream);
  k_deg<<<eb, 256, 0, stream>>>(row, tmp, E);
  k_scan1<<<nsb, 256, 0, stream>>>(tmp, bsum, N);
  k_scan2<<<1, 64, 0, stream>>>(bsum, nsb);
  k_scan3<<<nsb, 256, 0, stream>>>(tmp, bsum, rowptr, N);
  hipMemsetAsync(tmp, 0, (size_t)N * 4, stream);
  k_fill<<<eb, 256, 0, stream>>>(row, col, rowptr, tmp, cols_s, E);

  // neighbor mean + input projection -> buf0 (= x0 = h)
  k_nmean<<<nb4, 256, 0, stream>>>(x, rowptr, cols_s, nmean, N);
  k_h_in<<<(N * HID + 255) / 256, 256, 0, stream>>>(x, nmean, W_in, b_in, W_agg, b_agg, buf0, N);

  // layer 0: single-head (params [0]), residual = x0(buf0), bn[0] -> buf1
  k_gemm128<<<gemmb, 128, 0, stream>>>(buf0, sh_Wv, sh_b, buf2, N, 0);
  k_scores_sh<<<nb4, 256, 0, stream>>>(buf0, sh_asrc, sh_adst, ssrc, sdst, N);
  k_agg_sh<<<nb4, 256, 0, stream>>>(rowptr, cols_s, ssrc, sdst, buf2, buf0,
                                    bn_g, bn_bt, bn_m, bn_v, buf1, N);

  // layer 1: multi-head, bn[1], no residual -> buf0
  k_rearr<<<(HID * HID + 255) / 256, 256, 0, stream>>>(mh_Wv, Wcat);
  k_gemm128<<<gemmb, 128, 0, stream>>>(buf1, Wcat, mh_b, buf2, N, 0);
  k_scores_mh<<<nb4, 256, 0, stream>>>(buf1, mh_asrc, mh_adst, ssrc, sdst, N);
  k_agg_mh<<<nb4, 256, 0, stream>>>(rowptr, cols_s, ssrc, sdst, buf2,
                                    bn_g + HID, bn_bt + HID, bn_m + HID, bn_v + HID, buf0, N);

  // layer 2: single-head (params [1]), residual = buf0, bn[2] -> buf1
  k_gemm128<<<gemmb, 128, 0, stream>>>(buf0, sh_Wv + HID * HID, sh_b + HID, buf2, N, 0);
  k_scores_sh<<<nb4, 256, 0, stream>>>(buf0, sh_asrc + HID, sh_adst + HID, ssrc, sdst, N);
  k_agg_sh<<<nb4, 256, 0, stream>>>(rowptr, cols_s, ssrc, sdst, buf2, buf0,
                                    bn_g + 2 * HID, bn_bt + 2 * HID, bn_m + 2 * HID, bn_v + 2 * HID,
                                    buf1, N);

  // output head
  k_gemm128<<<gemmb, 128, 0, stream>>>(buf1, W_o1, b_o1, buf2, N, 1);
  k_out<<<nb4, 256, 0, stream>>>(buf2, W_o2, b_o2, x, out, N);
}

// Round 4
// 633.062 us; speedup vs baseline: 1.3513x; 1.0371x over previous
//
#include <hip/hip_runtime.h>
#include <math.h>

#define DIN 18
#define HID 128
#define NEGS 0.2f
#define BN_EPS 1e-5f
#define SCHUNK 2048

typedef unsigned short ushort_t;

__device__ __forceinline__ float leaky(float x){ return x >= 0.f ? x : NEGS * x; }

__device__ __forceinline__ float wred_sum(float v){
  #pragma unroll
  for (int off = 32; off; off >>= 1) v += __shfl_xor(v, off);
  return v;
}
__device__ __forceinline__ float wred_max(float v){
  #pragma unroll
  for (int off = 32; off; off >>= 1) v = fmaxf(v, __shfl_xor(v, off));
  return v;
}

__device__ __forceinline__ ushort_t f2bf(float f){
  union { float f; unsigned u; } v; v.f = f;
  unsigned r = v.u + 0x7FFFu + ((v.u >> 16) & 1u);
  return (ushort_t)(r >> 16);
}
__device__ __forceinline__ float bf_lo(unsigned p){ return __uint_as_float(p << 16); }
__device__ __forceinline__ float bf_hi(unsigned p){ return __uint_as_float(p & 0xFFFF0000u); }

__device__ __forceinline__ float sel4(float v0, float v1, float v2, float v3, int hd){
  float a = (hd & 1) ? v1 : v0;
  float b = (hd & 1) ? v3 : v2;
  return (hd & 2) ? b : a;
}

// ---------------- CSR build ----------------
__global__ void k_deg(const int* __restrict__ row, int* __restrict__ deg, int E){
  int i = blockIdx.x * blockDim.x + threadIdx.x;
  if (i < E) atomicAdd(&deg[row[i]], 1);
}

__global__ void k_scan1(const int* __restrict__ deg, int* __restrict__ bsum, int n){
  __shared__ int wtot[4];
  int tid = threadIdx.x, lane = tid & 63, wid = tid >> 6;
  int base = blockIdx.x * SCHUNK + tid * 8;
  int acc = 0;
  #pragma unroll
  for (int j = 0; j < 8; ++j){
    int i = base + j;
    if (i < n) acc += deg[i];
  }
  #pragma unroll
  for (int off = 32; off; off >>= 1) acc += __shfl_xor(acc, off);
  if (lane == 0) wtot[wid] = acc;
  __syncthreads();
  if (tid == 0) bsum[blockIdx.x] = wtot[0] + wtot[1] + wtot[2] + wtot[3];
}

__global__ void k_scan2(int* __restrict__ bsum, int nb){
  int lane = threadIdx.x;
  int carry = 0;
  for (int base = 0; base < nb; base += 64){
    int i = base + lane;
    int v = (i < nb) ? bsum[i] : 0;
    #pragma unroll
    for (int off = 1; off < 64; off <<= 1){
      int u = __shfl_up(v, off);
      if (lane >= off) v += u;
    }
    if (i < nb) bsum[i] = v + carry;
    carry += __shfl(v, 63);
  }
}

__global__ void k_scan3(const int* __restrict__ deg, const int* __restrict__ bsum,
                        int* __restrict__ rowptr, int n){
  __shared__ int wtot[4];
  int tid = threadIdx.x, lane = tid & 63, wid = tid >> 6;
  int base = blockIdx.x * SCHUNK + tid * 8;
  int l[8];
  int acc = 0;
  #pragma unroll
  for (int j = 0; j < 8; ++j){
    int i = base + j;
    acc += (i < n) ? deg[i] : 0;
    l[j] = acc;
  }
  int v = acc;
  #pragma unroll
  for (int off = 1; off < 64; off <<= 1){
    int u = __shfl_up(v, off);
    if (lane >= off) v += u;
  }
  if (lane == 63) wtot[wid] = v;
  __syncthreads();
  int woff = 0;
  for (int w = 0; w < wid; ++w) woff += wtot[w];
  int boff = (blockIdx.x == 0) ? 0 : bsum[blockIdx.x - 1];
  int tpre = boff + woff + (v - acc);
  #pragma unroll
  for (int j = 0; j < 8; ++j){
    int i = base + j;
    if (i < n) rowptr[i + 1] = tpre + l[j];
  }
  if (blockIdx.x == 0 && tid == 0) rowptr[0] = 0;
}

__global__ void k_fill(const int* __restrict__ row, const int* __restrict__ col,
                       const int* __restrict__ rowptr, int* __restrict__ cursor,
                       int* __restrict__ cols_s, int E){
  int i = blockIdx.x * blockDim.x + threadIdx.x;
  if (i < E){
    int r = row[i];
    int p = atomicAdd(&cursor[r], 1);
    cols_s[rowptr[r] + p] = col[i];
  }
}

// ---------------- neighbor mean ----------------
__global__ void k_nmean(const float* __restrict__ x, const int* __restrict__ rowptr,
                        const int* __restrict__ cols, float* __restrict__ nmean, int n){
  int node = blockIdx.x * 4 + (threadIdx.x >> 6);
  if (node >= n) return;
  int lane = threadIdx.x & 63;
  int s = rowptr[node], e = rowptr[node + 1];
  float acc = 0.f;
  for (int j0 = s; j0 < e; j0 += 64){
    int len = min(64, e - j0);
    int cv = (lane < len) ? cols[j0 + lane] : 0;
    for (int k = 0; k < len; ++k){
      int c = __shfl(cv, k);
      if (lane < DIN) acc += x[c * DIN + lane];
    }
  }
  if (lane < DIN){
    float d = (float)(e - s);
    nmean[node * DIN + lane] = acc / (d + 1e-8f);
  }
}

// ---------------- input projection ----------------
__global__ void k_h_in(const float* __restrict__ x, const float* __restrict__ nmean,
                       const float* __restrict__ Win, const float* __restrict__ bin,
                       const float* __restrict__ Wagg, const float* __restrict__ bagg,
                       float* __restrict__ out, int n){
  int i = blockIdx.x * blockDim.x + threadIdx.x;
  if (i >= n * HID) return;
  int node = i >> 7, c = i & 127;
  float acc = bin[c] + bagg[c];
  const float* xr = &x[node * DIN];
  const float* nr = &nmean[node * DIN];
  #pragma unroll
  for (int d = 0; d < DIN; ++d){
    acc += xr[d] * Win[d * HID + c] + nr[d] * Wagg[d * HID + c];
  }
  out[i] = acc;
}

// ---------------- 128x128 GEMM, 16 nodes/block ----------------
// mode 0: f32 out ; mode 1: leaky f32 out ; mode 2: packed bf16 out
__global__ void k_gemm128(const float* __restrict__ src, const float* __restrict__ W,
                          const float* __restrict__ bias, float* __restrict__ dst,
                          ushort_t* __restrict__ dstb, int n, int mode){
  __shared__ float hs[16][HID];
  int tid = threadIdx.x;
  int base = blockIdx.x * 16;
  #pragma unroll
  for (int k = 0; k < 16; ++k){
    int nd = base + k;
    hs[k][tid] = (nd < n) ? src[nd * HID + tid] : 0.f;
  }
  __syncthreads();
  float acc[16];
  #pragma unroll
  for (int k = 0; k < 16; ++k) acc[k] = 0.f;
  for (int d = 0; d < HID; ++d){
    float w = W[d * HID + tid];
    #pragma unroll
    for (int k = 0; k < 16; ++k) acc[k] += hs[k][d] * w;
  }
  float b = bias[tid];
  #pragma unroll
  for (int k = 0; k < 16; ++k){
    int nd = base + k;
    if (nd < n){
      float v = acc[k] + b;
      if (mode == 2){
        dstb[nd * HID + tid] = f2bf(v);
      } else {
        if (mode == 1) v = leaky(v);
        dst[nd * HID + tid] = v;
      }
    }
  }
}

// ---------------- rearrange mh_Wv [4][128][32] -> Wcat [128][128] ----------------
__global__ void k_rearr(const float* __restrict__ mhWv, float* __restrict__ Wcat){
  int i = blockIdx.x * blockDim.x + threadIdx.x;
  if (i >= HID * HID) return;
  int d = i >> 7, c = i & 127;
  Wcat[i] = mhWv[((c >> 5) * HID + d) * 32 + (c & 31)];
}

// ---------------- single-head scores ----------------
__global__ void k_scores_sh(const float* __restrict__ h, const float* __restrict__ asrc,
                            const float* __restrict__ adst,
                            float* __restrict__ ssrc, float* __restrict__ sdst, int n){
  int node = blockIdx.x * 4 + (threadIdx.x >> 6);
  if (node >= n) return;
  int lane = threadIdx.x & 63;
  float h0 = h[node * HID + lane], h1 = h[node * HID + 64 + lane];
  float ps = h0 * asrc[lane] + h1 * asrc[64 + lane];
  float pd = h0 * adst[lane] + h1 * adst[64 + lane];
  ps = wred_sum(ps);
  pd = wred_sum(pd);
  if (lane == 0){ ssrc[node] = ps; sdst[node] = pd; }
}

// ---------------- multi-head scores ----------------
__global__ void k_scores_mh(const float* __restrict__ h, const float* __restrict__ asrc,
                            const float* __restrict__ adst,
                            float* __restrict__ ssrc, float* __restrict__ sdst, int n){
  int node = blockIdx.x * 4 + (threadIdx.x >> 6);
  if (node >= n) return;
  int lane = threadIdx.x & 63;
  float h0 = h[node * HID + lane], h1 = h[node * HID + 64 + lane];
  #pragma unroll
  for (int hd = 0; hd < 4; ++hd){
    float ps = h0 * asrc[hd * HID + lane] + h1 * asrc[hd * HID + 64 + lane];
    float pd = h0 * adst[hd * HID + lane] + h1 * adst[hd * HID + 64 + lane];
    ps = wred_sum(ps);
    pd = wred_sum(pd);
    if (lane == 0){ ssrc[node * 4 + hd] = ps; sdst[node * 4 + hd] = pd; }
  }
}

// ---------------- single-head aggregation: online softmax, bf16 V ----------------
__global__ void k_agg_sh(const int* __restrict__ rowptr, const int* __restrict__ cols,
                         const float* __restrict__ ssrc, const float* __restrict__ sdst,
                         const ushort_t* __restrict__ hv, const float* __restrict__ resid,
                         const float* __restrict__ bng, const float* __restrict__ bnb,
                         const float* __restrict__ bnm, const float* __restrict__ bnv,
                         float* __restrict__ out, int n){
  int node = blockIdx.x * 4 + (threadIdx.x >> 6);
  if (node >= n) return;
  int lane = threadIdx.x & 63;
  int s = rowptr[node], e = rowptr[node + 1];
  float sq = ssrc[node];
  float m_run = -INFINITY, ssum = 0.f, a0 = 0.f, a1 = 0.f;
  for (int j0 = s; j0 < e; j0 += 64){
    int len = min(64, e - j0);
    int cv = (lane < len) ? cols[j0 + lane] : 0;
    float tv = (lane < len) ? leaky(sq + sdst[cv]) : -INFINITY;
    float cm = wred_max(tv);
    float m_new = fmaxf(m_run, cm);
    float sc = __expf(m_run - m_new);
    ssum *= sc; a0 *= sc; a1 *= sc;
    m_run = m_new;
    float ex = __expf(tv - m_run);
    ssum += wred_sum(ex);
    for (int k = 0; k < len; ++k){
      float al = __shfl(ex, k);
      int c = __shfl(cv, k);
      unsigned pv = *(const unsigned*)&hv[c * HID + 2 * lane];
      a0 += al * bf_lo(pv);
      a1 += al * bf_hi(pv);
    }
  }
  float inv = 1.f / (ssum + 1e-16f);
  a0 *= inv; a1 *= inv;
  int d0 = 2 * lane, d1 = 2 * lane + 1;
  float v0 = (a0 - bnm[d0]) * rsqrtf(bnv[d0] + BN_EPS) * bng[d0] + bnb[d0];
  float v1 = (a1 - bnm[d1]) * rsqrtf(bnv[d1] + BN_EPS) * bng[d1] + bnb[d1];
  if (resid){ v0 += resid[node * HID + d0]; v1 += resid[node * HID + d1]; }
  out[node * HID + d0] = leaky(v0);
  out[node * HID + d1] = leaky(v1);
}

// ---------------- multi-head aggregation: online softmax, bf16 V ----------------
__global__ void k_agg_mh(const int* __restrict__ rowptr, const int* __restrict__ cols,
                         const float* __restrict__ ssrc, const float* __restrict__ sdst,
                         const ushort_t* __restrict__ hv,
                         const float* __restrict__ bng, const float* __restrict__ bnb,
                         const float* __restrict__ bnm, const float* __restrict__ bnv,
                         float* __restrict__ out, int n){
  int node = blockIdx.x * 4 + (threadIdx.x >> 6);
  if (node >= n) return;
  int lane = threadIdx.x & 63;
  int s = rowptr[node], e = rowptr[node + 1];
  const float4 sq = *(const float4*)&ssrc[node * 4];
  int hd = lane >> 4;   // head of dims (2*lane, 2*lane+1)
  float m0 = -INFINITY, m1 = -INFINITY, m2 = -INFINITY, m3 = -INFINITY;
  float s0 = 0.f, s1 = 0.f, s2 = 0.f, s3 = 0.f;
  float a0 = 0.f, a1 = 0.f;
  for (int j0 = s; j0 < e; j0 += 64){
    int len = min(64, e - j0);
    int cv = (lane < len) ? cols[j0 + lane] : 0;
    float t0, t1, t2, t3;
    if (lane < len){
      float4 kd = *(const float4*)&sdst[cv * 4];
      t0 = leaky(sq.x + kd.x); t1 = leaky(sq.y + kd.y);
      t2 = leaky(sq.z + kd.z); t3 = leaky(sq.w + kd.w);
    } else {
      t0 = t1 = t2 = t3 = -INFINITY;
    }
    float n0 = fmaxf(m0, wred_max(t0));
    float n1 = fmaxf(m1, wred_max(t1));
    float n2 = fmaxf(m2, wred_max(t2));
    float n3 = fmaxf(m3, wred_max(t3));
    float c0 = __expf(m0 - n0), c1 = __expf(m1 - n1);
    float c2 = __expf(m2 - n2), c3 = __expf(m3 - n3);
    s0 *= c0; s1 *= c1; s2 *= c2; s3 *= c3;
    float ch = sel4(c0, c1, c2, c3, hd);
    a0 *= ch; a1 *= ch;
    m0 = n0; m1 = n1; m2 = n2; m3 = n3;
    float e0 = __expf(t0 - m0), e1 = __expf(t1 - m1);
    float e2 = __expf(t2 - m2), e3 = __expf(t3 - m3);
    s0 += wred_sum(e0); s1 += wred_sum(e1);
    s2 += wred_sum(e2); s3 += wred_sum(e3);
    for (int k = 0; k < len; ++k){
      float bx0 = __shfl(e0, k), bx1 = __shfl(e1, k);
      float bx2 = __shfl(e2, k), bx3 = __shfl(e3, k);
      int c = __shfl(cv, k);
      float al = sel4(bx0, bx1, bx2, bx3, hd);
      unsigned pv = *(const unsigned*)&hv[c * HID + 2 * lane];
      a0 += al * bf_lo(pv);
      a1 += al * bf_hi(pv);
    }
  }
  float i0 = 1.f / (s0 + 1e-16f), i1 = 1.f / (s1 + 1e-16f);
  float i2 = 1.f / (s2 + 1e-16f), i3 = 1.f / (s3 + 1e-16f);
  float ih = sel4(i0, i1, i2, i3, hd);
  a0 *= ih; a1 *= ih;
  int d0 = 2 * lane, d1 = 2 * lane + 1;
  float v0 = (a0 - bnm[d0]) * rsqrtf(bnv[d0] + BN_EPS) * bng[d0] + bnb[d0];
  float v1 = (a1 - bnm[d1]) * rsqrtf(bnv[d1] + BN_EPS) * bng[d1] + bnb[d1];
  out[node * HID + d0] = leaky(v0);
  out[node * HID + d1] = leaky(v1);
}

// ---------------- output head ----------------
__global__ void k_out(const float* __restrict__ o1, const float* __restrict__ Wo2,
                      const float* __restrict__ bo2, const float* __restrict__ x,
                      float* __restrict__ out, int n){
  int node = blockIdx.x * 4 + (threadIdx.x >> 6);
  if (node >= n) return;
  int lane = threadIdx.x & 63;
  float a = o1[node * HID + lane], b = o1[node * HID + 64 + lane];
  float p0 = a * Wo2[lane * 3 + 0] + b * Wo2[(lane + 64) * 3 + 0];
  float p1 = a * Wo2[lane * 3 + 1] + b * Wo2[(lane + 64) * 3 + 1];
  float p2 = a * Wo2[lane * 3 + 2] + b * Wo2[(lane + 64) * 3 + 2];
  p0 = wred_sum(p0); p1 = wred_sum(p1); p2 = wred_sum(p2);
  if (lane == 0){
    out[node * 3 + 0] = x[node * DIN + 15] + p0 + bo2[0];
    out[node * 3 + 1] = x[node * DIN + 16] + p1 + bo2[1];
    out[node * 3 + 2] = x[node * DIN + 17] + p2 + bo2[2];
  }
}

extern "C" void kernel_launch(void* const* d_in, const int* in_sizes, int n_in,
                              void* d_out, int out_size, void* d_ws, size_t ws_size,
                              hipStream_t stream){
  const float* x       = (const float*)d_in[0];
  const int*   ei      = (const int*)  d_in[1];
  const float* W_in    = (const float*)d_in[2];
  const float* b_in    = (const float*)d_in[3];
  const float* W_agg   = (const float*)d_in[4];
  const float* b_agg   = (const float*)d_in[5];
  const float* sh_Wv   = (const float*)d_in[6];
  const float* sh_b    = (const float*)d_in[7];
  const float* sh_asrc = (const float*)d_in[8];
  const float* sh_adst = (const float*)d_in[9];
  const float* mh_Wv   = (const float*)d_in[10];
  const float* mh_b    = (const float*)d_in[11];
  const float* mh_asrc = (const float*)d_in[12];
  const float* mh_adst = (const float*)d_in[13];
  const float* bn_g    = (const float*)d_in[14];
  const float* bn_bt   = (const float*)d_in[15];
  const float* bn_m    = (const float*)d_in[16];
  const float* bn_v    = (const float*)d_in[17];
  const float* W_o1    = (const float*)d_in[18];
  const float* b_o1    = (const float*)d_in[19];
  const float* W_o2    = (const float*)d_in[20];
  const float* b_o2    = (const float*)d_in[21];
  float* out = (float*)d_out;

  const int N = in_sizes[0] / DIN;
  const int E = in_sizes[1] / 2;
  const int* row = ei;
  const int* col = ei + E;

  char* w = (char*)d_ws;
  size_t off = 0;
  auto alloc = [&](size_t bytes) -> void* {
    void* p = w + off;
    off = (off + bytes + 255) & ~(size_t)255;
    return p;
  };
  int*      tmp    = (int*)     alloc((size_t)N * 4);
  int*      rowptr = (int*)     alloc((size_t)(N + 1) * 4);
  int*      cols_s = (int*)     alloc((size_t)E * 4);
  int*      bsum   = (int*)     alloc((size_t)1024 * 4);
  float*    nmean  = (float*)   alloc((size_t)N * DIN * 4);
  float*    ssrc   = (float*)   alloc((size_t)N * 4 * 4);
  float*    sdst   = (float*)   alloc((size_t)N * 4 * 4);
  float*    Wcat   = (float*)   alloc((size_t)HID * HID * 4);
  float*    buf0   = (float*)   alloc((size_t)N * HID * 4);
  float*    buf1   = (float*)   alloc((size_t)N * HID * 4);
  float*    buf2   = (float*)   alloc((size_t)N * HID * 4);
  ushort_t* hvb    = (ushort_t*)alloc((size_t)N * HID * 2);

  const int eb = (E + 255) / 256;
  const int nb4 = (N + 3) / 4;
  const int gemmb = (N + 15) / 16;
  const int nsb = (N + SCHUNK - 1) / SCHUNK;

  // CSR build
  hipMemsetAsync(tmp, 0, (size_t)N * 4, stream);
  k_deg<<<eb, 256, 0, stream>>>(row, tmp, E);
  k_scan1<<<nsb, 256, 0, stream>>>(tmp, bsum, N);
  k_scan2<<<1, 64, 0, stream>>>(bsum, nsb);
  k_scan3<<<nsb, 256, 0, stream>>>(tmp, bsum, rowptr, N);
  hipMemsetAsync(tmp, 0, (size_t)N * 4, stream);
  k_fill<<<eb, 256, 0, stream>>>(row, col, rowptr, tmp, cols_s, E);

  // neighbor mean + input projection -> buf0 (= x0 = h)
  k_nmean<<<nb4, 256, 0, stream>>>(x, rowptr, cols_s, nmean, N);
  k_h_in<<<(N * HID + 255) / 256, 256, 0, stream>>>(x, nmean, W_in, b_in, W_agg, b_agg, buf0, N);

  // layer 0: single-head (params [0]), residual = x0(buf0), bn[0] -> buf1
  k_gemm128<<<gemmb, 128, 0, stream>>>(buf0, sh_Wv, sh_b, nullptr, hvb, N, 2);
  k_scores_sh<<<nb4, 256, 0, stream>>>(buf0, sh_asrc, sh_adst, ssrc, sdst, N);
  k_agg_sh<<<nb4, 256, 0, stream>>>(rowptr, cols_s, ssrc, sdst, hvb, buf0,
                                    bn_g, bn_bt, bn_m, bn_v, buf1, N);

  // layer 1: multi-head, bn[1], no residual -> buf0
  k_rearr<<<(HID * HID + 255) / 256, 256, 0, stream>>>(mh_Wv, Wcat);
  k_gemm128<<<gemmb, 128, 0, stream>>>(buf1, Wcat, mh_b, nullptr, hvb, N, 2);
  k_scores_mh<<<nb4, 256, 0, stream>>>(buf1, mh_asrc, mh_adst, ssrc, sdst, N);
  k_agg_mh<<<nb4, 256, 0, stream>>>(rowptr, cols_s, ssrc, sdst, hvb,
                                    bn_g + HID, bn_bt + HID, bn_m + HID, bn_v + HID, buf0, N);

  // layer 2: single-head (params [1]), residual = buf0, bn[2] -> buf1
  k_gemm128<<<gemmb, 128, 0, stream>>>(buf0, sh_Wv + HID * HID, sh_b + HID, nullptr, hvb, N, 2);
  k_scores_sh<<<nb4, 256, 0, stream>>>(buf0, sh_asrc + HID, sh_adst + HID, ssrc, sdst, N);
  k_agg_sh<<<nb4, 256, 0, stream>>>(rowptr, cols_s, ssrc, sdst, hvb, buf0,
                                    bn_g + 2 * HID, bn_bt + 2 * HID, bn_m + 2 * HID, bn_v + 2 * HID,
                                    buf1, N);

  // output head
  k_gemm128<<<gemmb, 128, 0, stream>>>(buf1, W_o1, b_o1, buf2, nullptr, N, 1);
  k_out<<<nb4, 256, 0, stream>>>(buf2, W_o2, b_o2, x, out, N);
}

// Round 5
// 526.785 us; speedup vs baseline: 1.6240x; 1.2017x over previous
//
#include <hip/hip_runtime.h>
#include <math.h>

#define DIN 18
#define HID 128
#define NEGS 0.2f
#define BN_EPS 1e-5f
#define SCHUNK 2048

typedef unsigned short ushort_t;

__device__ __forceinline__ float leaky(float x){ return x >= 0.f ? x : NEGS * x; }

__device__ __forceinline__ float wred_sum(float v){
  #pragma unroll
  for (int off = 32; off; off >>= 1) v += __shfl_xor(v, off);
  return v;
}

__device__ __forceinline__ ushort_t f2bf(float f){
  union { float f; unsigned u; } v; v.f = f;
  unsigned r = v.u + 0x7FFFu + ((v.u >> 16) & 1u);
  return (ushort_t)(r >> 16);
}
__device__ __forceinline__ float bf_lo(unsigned p){ return __uint_as_float(p << 16); }
__device__ __forceinline__ float bf_hi(unsigned p){ return __uint_as_float(p & 0xFFFF0000u); }

__device__ __forceinline__ float sel4(float v0, float v1, float v2, float v3, int hd){
  float a = (hd & 1) ? v1 : v0;
  float b = (hd & 1) ? v3 : v2;
  return (hd & 2) ? b : a;
}

// ---------------- CSR build ----------------
__global__ void k_deg(const int* __restrict__ row, int* __restrict__ deg, int E){
  int i = blockIdx.x * blockDim.x + threadIdx.x;
  if (i < E) atomicAdd(&deg[row[i]], 1);
}

__global__ void k_scan1(const int* __restrict__ deg, int* __restrict__ bsum, int n){
  __shared__ int wtot[4];
  int tid = threadIdx.x, lane = tid & 63, wid = tid >> 6;
  int base = blockIdx.x * SCHUNK + tid * 8;
  int acc = 0;
  #pragma unroll
  for (int j = 0; j < 8; ++j){
    int i = base + j;
    if (i < n) acc += deg[i];
  }
  #pragma unroll
  for (int off = 32; off; off >>= 1) acc += __shfl_xor(acc, off);
  if (lane == 0) wtot[wid] = acc;
  __syncthreads();
  if (tid == 0) bsum[blockIdx.x] = wtot[0] + wtot[1] + wtot[2] + wtot[3];
}

__global__ void k_scan2(int* __restrict__ bsum, int nb){
  int lane = threadIdx.x;
  int carry = 0;
  for (int base = 0; base < nb; base += 64){
    int i = base + lane;
    int v = (i < nb) ? bsum[i] : 0;
    #pragma unroll
    for (int off = 1; off < 64; off <<= 1){
      int u = __shfl_up(v, off);
      if (lane >= off) v += u;
    }
    if (i < nb) bsum[i] = v + carry;
    carry += __shfl(v, 63);
  }
}

__global__ void k_scan3(const int* __restrict__ deg, const int* __restrict__ bsum,
                        int* __restrict__ rowptr, int n){
  __shared__ int wtot[4];
  int tid = threadIdx.x, lane = tid & 63, wid = tid >> 6;
  int base = blockIdx.x * SCHUNK + tid * 8;
  int l[8];
  int acc = 0;
  #pragma unroll
  for (int j = 0; j < 8; ++j){
    int i = base + j;
    acc += (i < n) ? deg[i] : 0;
    l[j] = acc;
  }
  int v = acc;
  #pragma unroll
  for (int off = 1; off < 64; off <<= 1){
    int u = __shfl_up(v, off);
    if (lane >= off) v += u;
  }
  if (lane == 63) wtot[wid] = v;
  __syncthreads();
  int woff = 0;
  for (int w = 0; w < wid; ++w) woff += wtot[w];
  int boff = (blockIdx.x == 0) ? 0 : bsum[blockIdx.x - 1];
  int tpre = boff + woff + (v - acc);
  #pragma unroll
  for (int j = 0; j < 8; ++j){
    int i = base + j;
    if (i < n) rowptr[i + 1] = tpre + l[j];
  }
  if (blockIdx.x == 0 && tid == 0) rowptr[0] = 0;
}

__global__ void k_fill(const int* __restrict__ row, const int* __restrict__ col,
                       const int* __restrict__ rowptr, int* __restrict__ cursor,
                       int* __restrict__ cols_s, int E){
  int i = blockIdx.x * blockDim.x + threadIdx.x;
  if (i < E){
    int r = row[i];
    int p = atomicAdd(&cursor[r], 1);
    cols_s[rowptr[r] + p] = col[i];
  }
}

// ---------------- neighbor mean (LDS-staged cols, unrolled gather) ----------------
__global__ void k_nmean(const float* __restrict__ x, const int* __restrict__ rowptr,
                        const int* __restrict__ cols, float* __restrict__ nmean, int n){
  __shared__ int s_cv[4][64];
  int wid = threadIdx.x >> 6;
  int node = blockIdx.x * 4 + wid;
  if (node >= n) return;
  int lane = threadIdx.x & 63;
  int s = rowptr[node], e = rowptr[node + 1];
  float acc = 0.f;
  for (int j0 = s; j0 < e; j0 += 64){
    int len = min(64, e - j0);
    int cv = (lane < len) ? cols[j0 + lane] : 0;
    s_cv[wid][lane] = cv;
    int k = 0;
    for (; k + 4 <= len; k += 4){
      int c0 = s_cv[wid][k], c1 = s_cv[wid][k+1], c2 = s_cv[wid][k+2], c3 = s_cv[wid][k+3];
      if (lane < DIN){
        float v0 = x[c0 * DIN + lane], v1 = x[c1 * DIN + lane];
        float v2 = x[c2 * DIN + lane], v3 = x[c3 * DIN + lane];
        acc += (v0 + v1) + (v2 + v3);
      }
    }
    for (; k < len; ++k){
      int c = s_cv[wid][k];
      if (lane < DIN) acc += x[c * DIN + lane];
    }
  }
  if (lane < DIN){
    float d = (float)(e - s);
    nmean[node * DIN + lane] = acc / (d + 1e-8f);
  }
}

// ---------------- input projection ----------------
__global__ void k_h_in(const float* __restrict__ x, const float* __restrict__ nmean,
                       const float* __restrict__ Win, const float* __restrict__ bin,
                       const float* __restrict__ Wagg, const float* __restrict__ bagg,
                       float* __restrict__ out, int n){
  int i = blockIdx.x * blockDim.x + threadIdx.x;
  if (i >= n * HID) return;
  int node = i >> 7, c = i & 127;
  float acc = bin[c] + bagg[c];
  const float* xr = &x[node * DIN];
  const float* nr = &nmean[node * DIN];
  #pragma unroll
  for (int d = 0; d < DIN; ++d){
    acc += xr[d] * Win[d * HID + c] + nr[d] * Wagg[d * HID + c];
  }
  out[i] = acc;
}

// ---------------- 128x128 GEMM, 16 nodes/block ----------------
// mode 0: f32 out ; mode 1: leaky f32 out ; mode 2: packed bf16 out
__global__ void k_gemm128(const float* __restrict__ src, const float* __restrict__ W,
                          const float* __restrict__ bias, float* __restrict__ dst,
                          ushort_t* __restrict__ dstb, int n, int mode){
  __shared__ float hs[16][HID];
  int tid = threadIdx.x;
  int base = blockIdx.x * 16;
  #pragma unroll
  for (int k = 0; k < 16; ++k){
    int nd = base + k;
    hs[k][tid] = (nd < n) ? src[nd * HID + tid] : 0.f;
  }
  __syncthreads();
  float acc[16];
  #pragma unroll
  for (int k = 0; k < 16; ++k) acc[k] = 0.f;
  for (int d = 0; d < HID; ++d){
    float w = W[d * HID + tid];
    #pragma unroll
    for (int k = 0; k < 16; ++k) acc[k] += hs[k][d] * w;
  }
  float b = bias[tid];
  #pragma unroll
  for (int k = 0; k < 16; ++k){
    int nd = base + k;
    if (nd < n){
      float v = acc[k] + b;
      if (mode == 2){
        dstb[nd * HID + tid] = f2bf(v);
      } else {
        if (mode == 1) v = leaky(v);
        dst[nd * HID + tid] = v;
      }
    }
  }
}

// ---------------- rearrange mh_Wv [4][128][32] -> Wcat [128][128] ----------------
__global__ void k_rearr(const float* __restrict__ mhWv, float* __restrict__ Wcat){
  int i = blockIdx.x * blockDim.x + threadIdx.x;
  if (i >= HID * HID) return;
  int d = i >> 7, c = i & 127;
  Wcat[i] = mhWv[((c >> 5) * HID + d) * 32 + (c & 31)];
}

// ---------------- single-head scores ----------------
__global__ void k_scores_sh(const float* __restrict__ h, const float* __restrict__ asrc,
                            const float* __restrict__ adst,
                            float* __restrict__ ssrc, float* __restrict__ sdst, int n){
  int node = blockIdx.x * 4 + (threadIdx.x >> 6);
  if (node >= n) return;
  int lane = threadIdx.x & 63;
  float h0 = h[node * HID + lane], h1 = h[node * HID + 64 + lane];
  float ps = h0 * asrc[lane] + h1 * asrc[64 + lane];
  float pd = h0 * adst[lane] + h1 * adst[64 + lane];
  ps = wred_sum(ps);
  pd = wred_sum(pd);
  if (lane == 0){ ssrc[node] = ps; sdst[node] = pd; }
}

// ---------------- multi-head scores ----------------
__global__ void k_scores_mh(const float* __restrict__ h, const float* __restrict__ asrc,
                            const float* __restrict__ adst,
                            float* __restrict__ ssrc, float* __restrict__ sdst, int n){
  int node = blockIdx.x * 4 + (threadIdx.x >> 6);
  if (node >= n) return;
  int lane = threadIdx.x & 63;
  float h0 = h[node * HID + lane], h1 = h[node * HID + 64 + lane];
  #pragma unroll
  for (int hd = 0; hd < 4; ++hd){
    float ps = h0 * asrc[hd * HID + lane] + h1 * asrc[hd * HID + 64 + lane];
    float pd = h0 * adst[hd * HID + lane] + h1 * adst[hd * HID + 64 + lane];
    ps = wred_sum(ps);
    pd = wred_sum(pd);
    if (lane == 0){ ssrc[node * 4 + hd] = ps; sdst[node * 4 + hd] = pd; }
  }
}

// ---------------- single-head aggregation: no-max softmax, LDS-staged, bf16 V ----------------
__global__ void k_agg_sh(const int* __restrict__ rowptr, const int* __restrict__ cols,
                         const float* __restrict__ ssrc, const float* __restrict__ sdst,
                         const ushort_t* __restrict__ hv, const float* __restrict__ resid,
                         const float* __restrict__ bng, const float* __restrict__ bnb,
                         const float* __restrict__ bnm, const float* __restrict__ bnv,
                         float* __restrict__ out, int n){
  __shared__ int   s_cv[4][64];
  __shared__ float s_ex[4][64];
  int wid = threadIdx.x >> 6;
  int node = blockIdx.x * 4 + wid;
  if (node >= n) return;
  int lane = threadIdx.x & 63;
  const unsigned* hv32 = (const unsigned*)hv;
  int s = rowptr[node], e = rowptr[node + 1];
  float sq = ssrc[node];
  float ssum = 0.f, a0 = 0.f, a1 = 0.f;
  for (int j0 = s; j0 < e; j0 += 64){
    int len = min(64, e - j0);
    int cv = 0; float ex = 0.f;
    if (lane < len){
      cv = cols[j0 + lane];
      ex = __expf(leaky(sq + sdst[cv]));
    }
    ssum += ex;
    s_cv[wid][lane] = cv;
    s_ex[wid][lane] = ex;
    int k = 0;
    for (; k + 4 <= len; k += 4){
      int c0 = s_cv[wid][k],   c1 = s_cv[wid][k+1];
      int c2 = s_cv[wid][k+2], c3 = s_cv[wid][k+3];
      float l0 = s_ex[wid][k],   l1 = s_ex[wid][k+1];
      float l2 = s_ex[wid][k+2], l3 = s_ex[wid][k+3];
      unsigned p0 = hv32[c0 * 64 + lane], p1 = hv32[c1 * 64 + lane];
      unsigned p2 = hv32[c2 * 64 + lane], p3 = hv32[c3 * 64 + lane];
      a0 += l0 * bf_lo(p0); a1 += l0 * bf_hi(p0);
      a0 += l1 * bf_lo(p1); a1 += l1 * bf_hi(p1);
      a0 += l2 * bf_lo(p2); a1 += l2 * bf_hi(p2);
      a0 += l3 * bf_lo(p3); a1 += l3 * bf_hi(p3);
    }
    for (; k < len; ++k){
      int c = s_cv[wid][k];
      float l = s_ex[wid][k];
      unsigned p = hv32[c * 64 + lane];
      a0 += l * bf_lo(p); a1 += l * bf_hi(p);
    }
  }
  ssum = wred_sum(ssum);
  float inv = 1.f / (ssum + 1e-16f);
  a0 *= inv; a1 *= inv;
  int d0 = 2 * lane, d1 = 2 * lane + 1;
  float v0 = (a0 - bnm[d0]) * rsqrtf(bnv[d0] + BN_EPS) * bng[d0] + bnb[d0];
  float v1 = (a1 - bnm[d1]) * rsqrtf(bnv[d1] + BN_EPS) * bng[d1] + bnb[d1];
  if (resid){ v0 += resid[node * HID + d0]; v1 += resid[node * HID + d1]; }
  out[node * HID + d0] = leaky(v0);
  out[node * HID + d1] = leaky(v1);
}

// ---------------- multi-head aggregation: no-max softmax, LDS-staged, bf16 V ----------------
__global__ void k_agg_mh(const int* __restrict__ rowptr, const int* __restrict__ cols,
                         const float* __restrict__ ssrc, const float* __restrict__ sdst,
                         const ushort_t* __restrict__ hv,
                         const float* __restrict__ bng, const float* __restrict__ bnb,
                         const float* __restrict__ bnm, const float* __restrict__ bnv,
                         float* __restrict__ out, int n){
  __shared__ int    s_cv[4][64];
  __shared__ float4 s_ex[4][64];   // [wave][edge] = exp for heads 0..3
  int wid = threadIdx.x >> 6;
  int node = blockIdx.x * 4 + wid;
  if (node >= n) return;
  int lane = threadIdx.x & 63;
  const unsigned* hv32 = (const unsigned*)hv;
  int s = rowptr[node], e = rowptr[node + 1];
  const float4 sq = *(const float4*)&ssrc[node * 4];
  int hd = lane >> 4;   // head of dims (2*lane, 2*lane+1)
  float s0 = 0.f, s1 = 0.f, s2 = 0.f, s3 = 0.f;
  float a0 = 0.f, a1 = 0.f;
  const float* exw = &s_ex[wid][0].x;   // flat view, edge k head h at [k*4+h]
  for (int j0 = s; j0 < e; j0 += 64){
    int len = min(64, e - j0);
    int cv = 0;
    float e0 = 0.f, e1 = 0.f, e2 = 0.f, e3 = 0.f;
    if (lane < len){
      cv = cols[j0 + lane];
      float4 kd = *(const float4*)&sdst[cv * 4];
      e0 = __expf(leaky(sq.x + kd.x)); e1 = __expf(leaky(sq.y + kd.y));
      e2 = __expf(leaky(sq.z + kd.z)); e3 = __expf(leaky(sq.w + kd.w));
    }
    s0 += e0; s1 += e1; s2 += e2; s3 += e3;
    s_cv[wid][lane] = cv;
    s_ex[wid][lane] = make_float4(e0, e1, e2, e3);
    int k = 0;
    for (; k + 4 <= len; k += 4){
      int c0 = s_cv[wid][k],   c1 = s_cv[wid][k+1];
      int c2 = s_cv[wid][k+2], c3 = s_cv[wid][k+3];
      float l0 = exw[(k)   * 4 + hd], l1 = exw[(k+1) * 4 + hd];
      float l2 = exw[(k+2) * 4 + hd], l3 = exw[(k+3) * 4 + hd];
      unsigned p0 = hv32[c0 * 64 + lane], p1 = hv32[c1 * 64 + lane];
      unsigned p2 = hv32[c2 * 64 + lane], p3 = hv32[c3 * 64 + lane];
      a0 += l0 * bf_lo(p0); a1 += l0 * bf_hi(p0);
      a0 += l1 * bf_lo(p1); a1 += l1 * bf_hi(p1);
      a0 += l2 * bf_lo(p2); a1 += l2 * bf_hi(p2);
      a0 += l3 * bf_lo(p3); a1 += l3 * bf_hi(p3);
    }
    for (; k < len; ++k){
      int c = s_cv[wid][k];
      float l = exw[k * 4 + hd];
      unsigned p = hv32[c * 64 + lane];
      a0 += l * bf_lo(p); a1 += l * bf_hi(p);
    }
  }
  s0 = wred_sum(s0); s1 = wred_sum(s1);
  s2 = wred_sum(s2); s3 = wred_sum(s3);
  float i0 = 1.f / (s0 + 1e-16f), i1 = 1.f / (s1 + 1e-16f);
  float i2 = 1.f / (s2 + 1e-16f), i3 = 1.f / (s3 + 1e-16f);
  float ih = sel4(i0, i1, i2, i3, hd);
  a0 *= ih; a1 *= ih;
  int d0 = 2 * lane, d1 = 2 * lane + 1;
  float v0 = (a0 - bnm[d0]) * rsqrtf(bnv[d0] + BN_EPS) * bng[d0] + bnb[d0];
  float v1 = (a1 - bnm[d1]) * rsqrtf(bnv[d1] + BN_EPS) * bng[d1] + bnb[d1];
  out[node * HID + d0] = leaky(v0);
  out[node * HID + d1] = leaky(v1);
}

// ---------------- output head ----------------
__global__ void k_out(const float* __restrict__ o1, const float* __restrict__ Wo2,
                      const float* __restrict__ bo2, const float* __restrict__ x,
                      float* __restrict__ out, int n){
  int node = blockIdx.x * 4 + (threadIdx.x >> 6);
  if (node >= n) return;
  int lane = threadIdx.x & 63;
  float a = o1[node * HID + lane], b = o1[node * HID + 64 + lane];
  float p0 = a * Wo2[lane * 3 + 0] + b * Wo2[(lane + 64) * 3 + 0];
  float p1 = a * Wo2[lane * 3 + 1] + b * Wo2[(lane + 64) * 3 + 1];
  float p2 = a * Wo2[lane * 3 + 2] + b * Wo2[(lane + 64) * 3 + 2];
  p0 = wred_sum(p0); p1 = wred_sum(p1); p2 = wred_sum(p2);
  if (lane == 0){
    out[node * 3 + 0] = x[node * DIN + 15] + p0 + bo2[0];
    out[node * 3 + 1] = x[node * DIN + 16] + p1 + bo2[1];
    out[node * 3 + 2] = x[node * DIN + 17] + p2 + bo2[2];
  }
}

extern "C" void kernel_launch(void* const* d_in, const int* in_sizes, int n_in,
                              void* d_out, int out_size, void* d_ws, size_t ws_size,
                              hipStream_t stream){
  const float* x       = (const float*)d_in[0];
  const int*   ei      = (const int*)  d_in[1];
  const float* W_in    = (const float*)d_in[2];
  const float* b_in    = (const float*)d_in[3];
  const float* W_agg   = (const float*)d_in[4];
  const float* b_agg   = (const float*)d_in[5];
  const float* sh_Wv   = (const float*)d_in[6];
  const float* sh_b    = (const float*)d_in[7];
  const float* sh_asrc = (const float*)d_in[8];
  const float* sh_adst = (const float*)d_in[9];
  const float* mh_Wv   = (const float*)d_in[10];
  const float* mh_b    = (const float*)d_in[11];
  const float* mh_asrc = (const float*)d_in[12];
  const float* mh_adst = (const float*)d_in[13];
  const float* bn_g    = (const float*)d_in[14];
  const float* bn_bt   = (const float*)d_in[15];
  const float* bn_m    = (const float*)d_in[16];
  const float* bn_v    = (const float*)d_in[17];
  const float* W_o1    = (const float*)d_in[18];
  const float* b_o1    = (const float*)d_in[19];
  const float* W_o2    = (const float*)d_in[20];
  const float* b_o2    = (const float*)d_in[21];
  float* out = (float*)d_out;

  const int N = in_sizes[0] / DIN;
  const int E = in_sizes[1] / 2;
  const int* row = ei;
  const int* col = ei + E;

  char* w = (char*)d_ws;
  size_t off = 0;
  auto alloc = [&](size_t bytes) -> void* {
    void* p = w + off;
    off = (off + bytes + 255) & ~(size_t)255;
    return p;
  };
  int*      tmp    = (int*)     alloc((size_t)N * 4);
  int*      rowptr = (int*)     alloc((size_t)(N + 1) * 4);
  int*      cols_s = (int*)     alloc((size_t)E * 4);
  int*      bsum   = (int*)     alloc((size_t)1024 * 4);
  float*    nmean  = (float*)   alloc((size_t)N * DIN * 4);
  float*    ssrc   = (float*)   alloc((size_t)N * 4 * 4);
  float*    sdst   = (float*)   alloc((size_t)N * 4 * 4);
  float*    Wcat   = (float*)   alloc((size_t)HID * HID * 4);
  float*    buf0   = (float*)   alloc((size_t)N * HID * 4);
  float*    buf1   = (float*)   alloc((size_t)N * HID * 4);
  float*    buf2   = (float*)   alloc((size_t)N * HID * 4);
  ushort_t* hvb    = (ushort_t*)alloc((size_t)N * HID * 2);

  const int eb = (E + 255) / 256;
  const int nb4 = (N + 3) / 4;
  const int gemmb = (N + 15) / 16;
  const int nsb = (N + SCHUNK - 1) / SCHUNK;

  // CSR build
  hipMemsetAsync(tmp, 0, (size_t)N * 4, stream);
  k_deg<<<eb, 256, 0, stream>>>(row, tmp, E);
  k_scan1<<<nsb, 256, 0, stream>>>(tmp, bsum, N);
  k_scan2<<<1, 64, 0, stream>>>(bsum, nsb);
  k_scan3<<<nsb, 256, 0, stream>>>(tmp, bsum, rowptr, N);
  hipMemsetAsync(tmp, 0, (size_t)N * 4, stream);
  k_fill<<<eb, 256, 0, stream>>>(row, col, rowptr, tmp, cols_s, E);

  // neighbor mean + input projection -> buf0 (= x0 = h)
  k_nmean<<<nb4, 256, 0, stream>>>(x, rowptr, cols_s, nmean, N);
  k_h_in<<<(N * HID + 255) / 256, 256, 0, stream>>>(x, nmean, W_in, b_in, W_agg, b_agg, buf0, N);

  // layer 0: single-head (params [0]), residual = x0(buf0), bn[0] -> buf1
  k_gemm128<<<gemmb, 128, 0, stream>>>(buf0, sh_Wv, sh_b, nullptr, hvb, N, 2);
  k_scores_sh<<<nb4, 256, 0, stream>>>(buf0, sh_asrc, sh_adst, ssrc, sdst, N);
  k_agg_sh<<<nb4, 256, 0, stream>>>(rowptr, cols_s, ssrc, sdst, hvb, buf0,
                                    bn_g, bn_bt, bn_m, bn_v, buf1, N);

  // layer 1: multi-head, bn[1], no residual -> buf0
  k_rearr<<<(HID * HID + 255) / 256, 256, 0, stream>>>(mh_Wv, Wcat);
  k_gemm128<<<gemmb, 128, 0, stream>>>(buf1, Wcat, mh_b, nullptr, hvb, N, 2);
  k_scores_mh<<<nb4, 256, 0, stream>>>(buf1, mh_asrc, mh_adst, ssrc, sdst, N);
  k_agg_mh<<<nb4, 256, 0, stream>>>(rowptr, cols_s, ssrc, sdst, hvb,
                                    bn_g + HID, bn_bt + HID, bn_m + HID, bn_v + HID, buf0, N);

  // layer 2: single-head (params [1]), residual = buf0, bn[2] -> buf1
  k_gemm128<<<gemmb, 128, 0, stream>>>(buf0, sh_Wv + HID * HID, sh_b + HID, nullptr, hvb, N, 2);
  k_scores_sh<<<nb4, 256, 0, stream>>>(buf0, sh_asrc + HID, sh_adst + HID, ssrc, sdst, N);
  k_agg_sh<<<nb4, 256, 0, stream>>>(rowptr, cols_s, ssrc, sdst, hvb, buf0,
                                    bn_g + 2 * HID, bn_bt + 2 * HID, bn_m + 2 * HID, bn_v + 2 * HID,
                                    buf1, N);

  // output head
  k_gemm128<<<gemmb, 128, 0, stream>>>(buf1, W_o1, b_o1, buf2, nullptr, N, 1);
  k_out<<<nb4, 256, 0, stream>>>(buf2, W_o2, b_o2, x, out, N);
}

// Round 6
// 509.210 us; speedup vs baseline: 1.6800x; 1.0345x over previous
//
#include <hip/hip_runtime.h>
#include <math.h>

#define DIN 18
#define HID 128
#define NEGS 0.2f
#define BN_EPS 1e-5f
#define SCHUNK 2048

typedef unsigned short ushort_t;

__device__ __forceinline__ float leaky(float x){ return x >= 0.f ? x : NEGS * x; }

__device__ __forceinline__ float wred_sum(float v){
  #pragma unroll
  for (int off = 32; off; off >>= 1) v += __shfl_xor(v, off);
  return v;
}

__device__ __forceinline__ ushort_t f2bf(float f){
  union { float f; unsigned u; } v; v.f = f;
  unsigned r = v.u + 0x7FFFu + ((v.u >> 16) & 1u);
  return (ushort_t)(r >> 16);
}
__device__ __forceinline__ float bf_lo(unsigned p){ return __uint_as_float(p << 16); }
__device__ __forceinline__ float bf_hi(unsigned p){ return __uint_as_float(p & 0xFFFF0000u); }

__device__ __forceinline__ float sel4(float v0, float v1, float v2, float v3, int hd){
  float a = (hd & 1) ? v1 : v0;
  float b = (hd & 1) ? v3 : v2;
  return (hd & 2) ? b : a;
}

// ---------------- CSR build ----------------
__global__ void k_deg(const int* __restrict__ row, int* __restrict__ deg, int E){
  int i = blockIdx.x * blockDim.x + threadIdx.x;
  if (i < E) atomicAdd(&deg[row[i]], 1);
}

__global__ void k_scan1(const int* __restrict__ deg, int* __restrict__ bsum, int n){
  __shared__ int wtot[4];
  int tid = threadIdx.x, lane = tid & 63, wid = tid >> 6;
  int base = blockIdx.x * SCHUNK + tid * 8;
  int acc = 0;
  #pragma unroll
  for (int j = 0; j < 8; ++j){
    int i = base + j;
    if (i < n) acc += deg[i];
  }
  #pragma unroll
  for (int off = 32; off; off >>= 1) acc += __shfl_xor(acc, off);
  if (lane == 0) wtot[wid] = acc;
  __syncthreads();
  if (tid == 0) bsum[blockIdx.x] = wtot[0] + wtot[1] + wtot[2] + wtot[3];
}

__global__ void k_scan2(int* __restrict__ bsum, int nb){
  int lane = threadIdx.x;
  int carry = 0;
  for (int base = 0; base < nb; base += 64){
    int i = base + lane;
    int v = (i < nb) ? bsum[i] : 0;
    #pragma unroll
    for (int off = 1; off < 64; off <<= 1){
      int u = __shfl_up(v, off);
      if (lane >= off) v += u;
    }
    if (i < nb) bsum[i] = v + carry;
    carry += __shfl(v, 63);
  }
}

__global__ void k_scan3(const int* __restrict__ deg, const int* __restrict__ bsum,
                        int* __restrict__ rowptr, int n){
  __shared__ int wtot[4];
  int tid = threadIdx.x, lane = tid & 63, wid = tid >> 6;
  int base = blockIdx.x * SCHUNK + tid * 8;
  int l[8];
  int acc = 0;
  #pragma unroll
  for (int j = 0; j < 8; ++j){
    int i = base + j;
    acc += (i < n) ? deg[i] : 0;
    l[j] = acc;
  }
  int v = acc;
  #pragma unroll
  for (int off = 1; off < 64; off <<= 1){
    int u = __shfl_up(v, off);
    if (lane >= off) v += u;
  }
  if (lane == 63) wtot[wid] = v;
  __syncthreads();
  int woff = 0;
  for (int w = 0; w < wid; ++w) woff += wtot[w];
  int boff = (blockIdx.x == 0) ? 0 : bsum[blockIdx.x - 1];
  int tpre = boff + woff + (v - acc);
  #pragma unroll
  for (int j = 0; j < 8; ++j){
    int i = base + j;
    if (i < n) rowptr[i + 1] = tpre + l[j];
  }
  if (blockIdx.x == 0 && tid == 0) rowptr[0] = 0;
}

__global__ void k_fill(const int* __restrict__ row, const int* __restrict__ col,
                       const int* __restrict__ rowptr, int* __restrict__ cursor,
                       int* __restrict__ cols_s, int E){
  int i = blockIdx.x * blockDim.x + threadIdx.x;
  if (i < E){
    int r = row[i];
    int p = atomicAdd(&cursor[r], 1);
    cols_s[rowptr[r] + p] = col[i];
  }
}

// ---------------- neighbor mean (LDS-staged cols, unrolled gather) ----------------
__global__ void k_nmean(const float* __restrict__ x, const int* __restrict__ rowptr,
                        const int* __restrict__ cols, float* __restrict__ nmean, int n){
  __shared__ int s_cv[4][64];
  int wid = threadIdx.x >> 6;
  int node = blockIdx.x * 4 + wid;
  if (node >= n) return;
  int lane = threadIdx.x & 63;
  int s = rowptr[node], e = rowptr[node + 1];
  float acc = 0.f;
  for (int j0 = s; j0 < e; j0 += 64){
    int len = min(64, e - j0);
    int cv = (lane < len) ? cols[j0 + lane] : 0;
    s_cv[wid][lane] = cv;
    int k = 0;
    for (; k + 4 <= len; k += 4){
      int c0 = s_cv[wid][k], c1 = s_cv[wid][k+1], c2 = s_cv[wid][k+2], c3 = s_cv[wid][k+3];
      if (lane < DIN){
        float v0 = x[c0 * DIN + lane], v1 = x[c1 * DIN + lane];
        float v2 = x[c2 * DIN + lane], v3 = x[c3 * DIN + lane];
        acc += (v0 + v1) + (v2 + v3);
      }
    }
    for (; k < len; ++k){
      int c = s_cv[wid][k];
      if (lane < DIN) acc += x[c * DIN + lane];
    }
  }
  if (lane < DIN){
    float d = (float)(e - s);
    nmean[node * DIN + lane] = acc / (d + 1e-8f);
  }
}

// ---------------- input projection: one wave per node, shfl-broadcast x ----------------
__global__ void k_h_in(const float* __restrict__ x, const float* __restrict__ nmean,
                       const float* __restrict__ Win, const float* __restrict__ bin,
                       const float* __restrict__ Wagg, const float* __restrict__ bagg,
                       float* __restrict__ out, int n){
  int wid = threadIdx.x >> 6;
  int node = blockIdx.x * 4 + wid;
  if (node >= n) return;
  int lane = threadIdx.x & 63;
  // lanes 0..17 hold x row, lanes 18..35 hold nmean row
  float xv = 0.f;
  if (lane < DIN) xv = x[node * DIN + lane];
  else if (lane < 2 * DIN) xv = nmean[node * DIN + (lane - DIN)];
  float acc0 = bin[lane]      + bagg[lane];
  float acc1 = bin[64 + lane] + bagg[64 + lane];
  #pragma unroll
  for (int d = 0; d < DIN; ++d){
    float xd = __shfl(xv, d);
    float nd = __shfl(xv, DIN + d);
    acc0 += xd * Win[d * HID + lane]       + nd * Wagg[d * HID + lane];
    acc1 += xd * Win[d * HID + 64 + lane]  + nd * Wagg[d * HID + 64 + lane];
  }
  out[node * HID + lane]      = acc0;
  out[node * HID + 64 + lane] = acc1;
}

// ---------------- 128x128 GEMM, 16 nodes/block ----------------
// mode 0: f32 out ; mode 1: leaky f32 out ; mode 2: packed bf16 out
__global__ void k_gemm128(const float* __restrict__ src, const float* __restrict__ W,
                          const float* __restrict__ bias, float* __restrict__ dst,
                          ushort_t* __restrict__ dstb, int n, int mode){
  __shared__ float hs[16][HID];
  int tid = threadIdx.x;
  int base = blockIdx.x * 16;
  #pragma unroll
  for (int k = 0; k < 16; ++k){
    int nd = base + k;
    hs[k][tid] = (nd < n) ? src[nd * HID + tid] : 0.f;
  }
  __syncthreads();
  float acc[16];
  #pragma unroll
  for (int k = 0; k < 16; ++k) acc[k] = 0.f;
  for (int d = 0; d < HID; ++d){
    float w = W[d * HID + tid];
    #pragma unroll
    for (int k = 0; k < 16; ++k) acc[k] += hs[k][d] * w;
  }
  float b = bias[tid];
  #pragma unroll
  for (int k = 0; k < 16; ++k){
    int nd = base + k;
    if (nd < n){
      float v = acc[k] + b;
      if (mode == 2){
        dstb[nd * HID + tid] = f2bf(v);
      } else {
        if (mode == 1) v = leaky(v);
        dst[nd * HID + tid] = v;
      }
    }
  }
}

// ---------------- rearrange mh_Wv [4][128][32] -> Wcat [128][128] ----------------
__global__ void k_rearr(const float* __restrict__ mhWv, float* __restrict__ Wcat){
  int i = blockIdx.x * blockDim.x + threadIdx.x;
  if (i >= HID * HID) return;
  int d = i >> 7, c = i & 127;
  Wcat[i] = mhWv[((c >> 5) * HID + d) * 32 + (c & 31)];
}

// ---------------- single-head scores ----------------
__global__ void k_scores_sh(const float* __restrict__ h, const float* __restrict__ asrc,
                            const float* __restrict__ adst,
                            float* __restrict__ ssrc, float* __restrict__ sdst, int n){
  int node = blockIdx.x * 4 + (threadIdx.x >> 6);
  if (node >= n) return;
  int lane = threadIdx.x & 63;
  float h0 = h[node * HID + lane], h1 = h[node * HID + 64 + lane];
  float ps = h0 * asrc[lane] + h1 * asrc[64 + lane];
  float pd = h0 * adst[lane] + h1 * adst[64 + lane];
  ps = wred_sum(ps);
  pd = wred_sum(pd);
  if (lane == 0){ ssrc[node] = ps; sdst[node] = pd; }
}

// ---------------- multi-head scores ----------------
__global__ void k_scores_mh(const float* __restrict__ h, const float* __restrict__ asrc,
                            const float* __restrict__ adst,
                            float* __restrict__ ssrc, float* __restrict__ sdst, int n){
  int node = blockIdx.x * 4 + (threadIdx.x >> 6);
  if (node >= n) return;
  int lane = threadIdx.x & 63;
  float h0 = h[node * HID + lane], h1 = h[node * HID + 64 + lane];
  #pragma unroll
  for (int hd = 0; hd < 4; ++hd){
    float ps = h0 * asrc[hd * HID + lane] + h1 * asrc[hd * HID + 64 + lane];
    float pd = h0 * adst[hd * HID + lane] + h1 * adst[hd * HID + 64 + lane];
    ps = wred_sum(ps);
    pd = wred_sum(pd);
    if (lane == 0){ ssrc[node * 4 + hd] = ps; sdst[node * 4 + hd] = pd; }
  }
}

// ---------------- single-head aggregation: no-max softmax, LDS-staged, bf16 V ----------------
__global__ void k_agg_sh(const int* __restrict__ rowptr, const int* __restrict__ cols,
                         const float* __restrict__ ssrc, const float* __restrict__ sdst,
                         const ushort_t* __restrict__ hv, const float* __restrict__ resid,
                         const float* __restrict__ bng, const float* __restrict__ bnb,
                         const float* __restrict__ bnm, const float* __restrict__ bnv,
                         float* __restrict__ out, int n){
  __shared__ int   s_cv[4][64];
  __shared__ float s_ex[4][64];
  int wid = threadIdx.x >> 6;
  int node = blockIdx.x * 4 + wid;
  if (node >= n) return;
  int lane = threadIdx.x & 63;
  const unsigned* hv32 = (const unsigned*)hv;
  int s = rowptr[node], e = rowptr[node + 1];
  float sq = ssrc[node];
  float ssum = 0.f, a0 = 0.f, a1 = 0.f;
  for (int j0 = s; j0 < e; j0 += 64){
    int len = min(64, e - j0);
    int cv = 0; float ex = 0.f;
    if (lane < len){
      cv = cols[j0 + lane];
      ex = __expf(leaky(sq + sdst[cv]));
    }
    ssum += ex;
    s_cv[wid][lane] = cv;
    s_ex[wid][lane] = ex;
    int k = 0;
    for (; k + 4 <= len; k += 4){
      int c0 = s_cv[wid][k],   c1 = s_cv[wid][k+1];
      int c2 = s_cv[wid][k+2], c3 = s_cv[wid][k+3];
      float l0 = s_ex[wid][k],   l1 = s_ex[wid][k+1];
      float l2 = s_ex[wid][k+2], l3 = s_ex[wid][k+3];
      unsigned p0 = hv32[c0 * 64 + lane], p1 = hv32[c1 * 64 + lane];
      unsigned p2 = hv32[c2 * 64 + lane], p3 = hv32[c3 * 64 + lane];
      a0 += l0 * bf_lo(p0); a1 += l0 * bf_hi(p0);
      a0 += l1 * bf_lo(p1); a1 += l1 * bf_hi(p1);
      a0 += l2 * bf_lo(p2); a1 += l2 * bf_hi(p2);
      a0 += l3 * bf_lo(p3); a1 += l3 * bf_hi(p3);
    }
    for (; k < len; ++k){
      int c = s_cv[wid][k];
      float l = s_ex[wid][k];
      unsigned p = hv32[c * 64 + lane];
      a0 += l * bf_lo(p); a1 += l * bf_hi(p);
    }
  }
  ssum = wred_sum(ssum);
  float inv = 1.f / (ssum + 1e-16f);
  a0 *= inv; a1 *= inv;
  int d0 = 2 * lane, d1 = 2 * lane + 1;
  float v0 = (a0 - bnm[d0]) * rsqrtf(bnv[d0] + BN_EPS) * bng[d0] + bnb[d0];
  float v1 = (a1 - bnm[d1]) * rsqrtf(bnv[d1] + BN_EPS) * bng[d1] + bnb[d1];
  if (resid){ v0 += resid[node * HID + d0]; v1 += resid[node * HID + d1]; }
  out[node * HID + d0] = leaky(v0);
  out[node * HID + d1] = leaky(v1);
}

// ---------------- multi-head aggregation: no-max softmax, LDS-staged, bf16 V ----------------
__global__ void k_agg_mh(const int* __restrict__ rowptr, const int* __restrict__ cols,
                         const float* __restrict__ ssrc, const float* __restrict__ sdst,
                         const ushort_t* __restrict__ hv,
                         const float* __restrict__ bng, const float* __restrict__ bnb,
                         const float* __restrict__ bnm, const float* __restrict__ bnv,
                         float* __restrict__ out, int n){
  __shared__ int    s_cv[4][64];
  __shared__ float4 s_ex[4][64];   // [wave][edge] = exp for heads 0..3
  int wid = threadIdx.x >> 6;
  int node = blockIdx.x * 4 + wid;
  if (node >= n) return;
  int lane = threadIdx.x & 63;
  const unsigned* hv32 = (const unsigned*)hv;
  int s = rowptr[node], e = rowptr[node + 1];
  const float4 sq = *(const float4*)&ssrc[node * 4];
  int hd = lane >> 4;   // head of dims (2*lane, 2*lane+1)
  float s0 = 0.f, s1 = 0.f, s2 = 0.f, s3 = 0.f;
  float a0 = 0.f, a1 = 0.f;
  const float* exw = &s_ex[wid][0].x;   // flat view, edge k head h at [k*4+h]
  for (int j0 = s; j0 < e; j0 += 64){
    int len = min(64, e - j0);
    int cv = 0;
    float e0 = 0.f, e1 = 0.f, e2 = 0.f, e3 = 0.f;
    if (lane < len){
      cv = cols[j0 + lane];
      float4 kd = *(const float4*)&sdst[cv * 4];
      e0 = __expf(leaky(sq.x + kd.x)); e1 = __expf(leaky(sq.y + kd.y));
      e2 = __expf(leaky(sq.z + kd.z)); e3 = __expf(leaky(sq.w + kd.w));
    }
    s0 += e0; s1 += e1; s2 += e2; s3 += e3;
    s_cv[wid][lane] = cv;
    s_ex[wid][lane] = make_float4(e0, e1, e2, e3);
    int k = 0;
    for (; k + 4 <= len; k += 4){
      int c0 = s_cv[wid][k],   c1 = s_cv[wid][k+1];
      int c2 = s_cv[wid][k+2], c3 = s_cv[wid][k+3];
      float l0 = exw[(k)   * 4 + hd], l1 = exw[(k+1) * 4 + hd];
      float l2 = exw[(k+2) * 4 + hd], l3 = exw[(k+3) * 4 + hd];
      unsigned p0 = hv32[c0 * 64 + lane], p1 = hv32[c1 * 64 + lane];
      unsigned p2 = hv32[c2 * 64 + lane], p3 = hv32[c3 * 64 + lane];
      a0 += l0 * bf_lo(p0); a1 += l0 * bf_hi(p0);
      a0 += l1 * bf_lo(p1); a1 += l1 * bf_hi(p1);
      a0 += l2 * bf_lo(p2); a1 += l2 * bf_hi(p2);
      a0 += l3 * bf_lo(p3); a1 += l3 * bf_hi(p3);
    }
    for (; k < len; ++k){
      int c = s_cv[wid][k];
      float l = exw[k * 4 + hd];
      unsigned p = hv32[c * 64 + lane];
      a0 += l * bf_lo(p); a1 += l * bf_hi(p);
    }
  }
  s0 = wred_sum(s0); s1 = wred_sum(s1);
  s2 = wred_sum(s2); s3 = wred_sum(s3);
  float i0 = 1.f / (s0 + 1e-16f), i1 = 1.f / (s1 + 1e-16f);
  float i2 = 1.f / (s2 + 1e-16f), i3 = 1.f / (s3 + 1e-16f);
  float ih = sel4(i0, i1, i2, i3, hd);
  a0 *= ih; a1 *= ih;
  int d0 = 2 * lane, d1 = 2 * lane + 1;
  float v0 = (a0 - bnm[d0]) * rsqrtf(bnv[d0] + BN_EPS) * bng[d0] + bnb[d0];
  float v1 = (a1 - bnm[d1]) * rsqrtf(bnv[d1] + BN_EPS) * bng[d1] + bnb[d1];
  out[node * HID + d0] = leaky(v0);
  out[node * HID + d1] = leaky(v1);
}

// ---------------- output head ----------------
__global__ void k_out(const float* __restrict__ o1, const float* __restrict__ Wo2,
                      const float* __restrict__ bo2, const float* __restrict__ x,
                      float* __restrict__ out, int n){
  int node = blockIdx.x * 4 + (threadIdx.x >> 6);
  if (node >= n) return;
  int lane = threadIdx.x & 63;
  float a = o1[node * HID + lane], b = o1[node * HID + 64 + lane];
  float p0 = a * Wo2[lane * 3 + 0] + b * Wo2[(lane + 64) * 3 + 0];
  float p1 = a * Wo2[lane * 3 + 1] + b * Wo2[(lane + 64) * 3 + 1];
  float p2 = a * Wo2[lane * 3 + 2] + b * Wo2[(lane + 64) * 3 + 2];
  p0 = wred_sum(p0); p1 = wred_sum(p1); p2 = wred_sum(p2);
  if (lane == 0){
    out[node * 3 + 0] = x[node * DIN + 15] + p0 + bo2[0];
    out[node * 3 + 1] = x[node * DIN + 16] + p1 + bo2[1];
    out[node * 3 + 2] = x[node * DIN + 17] + p2 + bo2[2];
  }
}

extern "C" void kernel_launch(void* const* d_in, const int* in_sizes, int n_in,
                              void* d_out, int out_size, void* d_ws, size_t ws_size,
                              hipStream_t stream){
  const float* x       = (const float*)d_in[0];
  const int*   ei      = (const int*)  d_in[1];
  const float* W_in    = (const float*)d_in[2];
  const float* b_in    = (const float*)d_in[3];
  const float* W_agg   = (const float*)d_in[4];
  const float* b_agg   = (const float*)d_in[5];
  const float* sh_Wv   = (const float*)d_in[6];
  const float* sh_b    = (const float*)d_in[7];
  const float* sh_asrc = (const float*)d_in[8];
  const float* sh_adst = (const float*)d_in[9];
  const float* mh_Wv   = (const float*)d_in[10];
  const float* mh_b    = (const float*)d_in[11];
  const float* mh_asrc = (const float*)d_in[12];
  const float* mh_adst = (const float*)d_in[13];
  const float* bn_g    = (const float*)d_in[14];
  const float* bn_bt   = (const float*)d_in[15];
  const float* bn_m    = (const float*)d_in[16];
  const float* bn_v    = (const float*)d_in[17];
  const float* W_o1    = (const float*)d_in[18];
  const float* b_o1    = (const float*)d_in[19];
  const float* W_o2    = (const float*)d_in[20];
  const float* b_o2    = (const float*)d_in[21];
  float* out = (float*)d_out;

  const int N = in_sizes[0] / DIN;
  const int E = in_sizes[1] / 2;
  const int* row = ei;
  const int* col = ei + E;

  char* w = (char*)d_ws;
  size_t off = 0;
  auto alloc = [&](size_t bytes) -> void* {
    void* p = w + off;
    off = (off + bytes + 255) & ~(size_t)255;
    return p;
  };
  int*      tmp    = (int*)     alloc((size_t)N * 4);
  int*      rowptr = (int*)     alloc((size_t)(N + 1) * 4);
  int*      cols_s = (int*)     alloc((size_t)E * 4);
  int*      bsum   = (int*)     alloc((size_t)1024 * 4);
  float*    nmean  = (float*)   alloc((size_t)N * DIN * 4);
  float*    ssrc   = (float*)   alloc((size_t)N * 4 * 4);
  float*    sdst   = (float*)   alloc((size_t)N * 4 * 4);
  float*    Wcat   = (float*)   alloc((size_t)HID * HID * 4);
  float*    buf0   = (float*)   alloc((size_t)N * HID * 4);
  float*    buf1   = (float*)   alloc((size_t)N * HID * 4);
  float*    buf2   = (float*)   alloc((size_t)N * HID * 4);
  ushort_t* hvb    = (ushort_t*)alloc((size_t)N * HID * 2);

  const int eb = (E + 255) / 256;
  const int nb4 = (N + 3) / 4;
  const int gemmb = (N + 15) / 16;
  const int nsb = (N + SCHUNK - 1) / SCHUNK;

  // CSR build
  hipMemsetAsync(tmp, 0, (size_t)N * 4, stream);
  k_deg<<<eb, 256, 0, stream>>>(row, tmp, E);
  k_scan1<<<nsb, 256, 0, stream>>>(tmp, bsum, N);
  k_scan2<<<1, 64, 0, stream>>>(bsum, nsb);
  k_scan3<<<nsb, 256, 0, stream>>>(tmp, bsum, rowptr, N);
  hipMemsetAsync(tmp, 0, (size_t)N * 4, stream);
  k_fill<<<eb, 256, 0, stream>>>(row, col, rowptr, tmp, cols_s, E);

  // neighbor mean + input projection -> buf0 (= x0 = h)
  k_nmean<<<nb4, 256, 0, stream>>>(x, rowptr, cols_s, nmean, N);
  k_h_in<<<nb4, 256, 0, stream>>>(x, nmean, W_in, b_in, W_agg, b_agg, buf0, N);

  // layer 0: single-head (params [0]), residual = x0(buf0), bn[0] -> buf1
  k_gemm128<<<gemmb, 128, 0, stream>>>(buf0, sh_Wv, sh_b, nullptr, hvb, N, 2);
  k_scores_sh<<<nb4, 256, 0, stream>>>(buf0, sh_asrc, sh_adst, ssrc, sdst, N);
  k_agg_sh<<<nb4, 256, 0, stream>>>(rowptr, cols_s, ssrc, sdst, hvb, buf0,
                                    bn_g, bn_bt, bn_m, bn_v, buf1, N);

  // layer 1: multi-head, bn[1], no residual -> buf0
  k_rearr<<<(HID * HID + 255) / 256, 256, 0, stream>>>(mh_Wv, Wcat);
  k_gemm128<<<gemmb, 128, 0, stream>>>(buf1, Wcat, mh_b, nullptr, hvb, N, 2);
  k_scores_mh<<<nb4, 256, 0, stream>>>(buf1, mh_asrc, mh_adst, ssrc, sdst, N);
  k_agg_mh<<<nb4, 256, 0, stream>>>(rowptr, cols_s, ssrc, sdst, hvb,
                                    bn_g + HID, bn_bt + HID, bn_m + HID, bn_v + HID, buf0, N);

  // layer 2: single-head (params [1]), residual = buf0, bn[2] -> buf1
  k_gemm128<<<gemmb, 128, 0, stream>>>(buf0, sh_Wv + HID * HID, sh_b + HID, nullptr, hvb, N, 2);
  k_scores_sh<<<nb4, 256, 0, stream>>>(buf0, sh_asrc + HID, sh_adst + HID, ssrc, sdst, N);
  k_agg_sh<<<nb4, 256, 0, stream>>>(rowptr, cols_s, ssrc, sdst, hvb, buf0,
                                    bn_g + 2 * HID, bn_bt + 2 * HID, bn_m + 2 * HID, bn_v + 2 * HID,
                                    buf1, N);

  // output head
  k_gemm128<<<gemmb, 128, 0, stream>>>(buf1, W_o1, b_o1, buf2, nullptr, N, 1);
  k_out<<<nb4, 256, 0, stream>>>(buf2, W_o2, b_o2, x, out, N);
}

// Round 7
// 434.643 us; speedup vs baseline: 1.9682x; 1.1716x over previous
//
#include <hip/hip_runtime.h>
#include <math.h>

#define DIN 18
#define HID 128
#define NEGS 0.2f
#define BN_EPS 1e-5f
#define SCHUNK 2048

typedef unsigned short ushort_t;
typedef __attribute__((ext_vector_type(8))) short bf16x8;
typedef __attribute__((ext_vector_type(4))) float f32x4;

__device__ __forceinline__ float leaky(float x){ return x >= 0.f ? x : NEGS * x; }

__device__ __forceinline__ float wred_sum(float v){
  #pragma unroll
  for (int off = 32; off; off >>= 1) v += __shfl_xor(v, off);
  return v;
}

__device__ __forceinline__ ushort_t f2bf(float f){
  union { float f; unsigned u; } v; v.f = f;
  unsigned r = v.u + 0x7FFFu + ((v.u >> 16) & 1u);
  return (ushort_t)(r >> 16);
}
__device__ __forceinline__ float bf_lo(unsigned p){ return __uint_as_float(p << 16); }
__device__ __forceinline__ float bf_hi(unsigned p){ return __uint_as_float(p & 0xFFFF0000u); }

__device__ __forceinline__ float sel4(float v0, float v1, float v2, float v3, int hd){
  float a = (hd & 1) ? v1 : v0;
  float b = (hd & 1) ? v3 : v2;
  return (hd & 2) ? b : a;
}

// ---------------- CSR build ----------------
__global__ void k_deg(const int* __restrict__ row, int* __restrict__ deg, int E){
  int i = blockIdx.x * blockDim.x + threadIdx.x;
  if (i < E) atomicAdd(&deg[row[i]], 1);
}

__global__ void k_scan1(const int* __restrict__ deg, int* __restrict__ bsum, int n){
  __shared__ int wtot[4];
  int tid = threadIdx.x, lane = tid & 63, wid = tid >> 6;
  int base = blockIdx.x * SCHUNK + tid * 8;
  int acc = 0;
  #pragma unroll
  for (int j = 0; j < 8; ++j){
    int i = base + j;
    if (i < n) acc += deg[i];
  }
  #pragma unroll
  for (int off = 32; off; off >>= 1) acc += __shfl_xor(acc, off);
  if (lane == 0) wtot[wid] = acc;
  __syncthreads();
  if (tid == 0) bsum[blockIdx.x] = wtot[0] + wtot[1] + wtot[2] + wtot[3];
}

__global__ void k_scan2(int* __restrict__ bsum, int nb){
  int lane = threadIdx.x;
  int carry = 0;
  for (int base = 0; base < nb; base += 64){
    int i = base + lane;
    int v = (i < nb) ? bsum[i] : 0;
    #pragma unroll
    for (int off = 1; off < 64; off <<= 1){
      int u = __shfl_up(v, off);
      if (lane >= off) v += u;
    }
    if (i < nb) bsum[i] = v + carry;
    carry += __shfl(v, 63);
  }
}

__global__ void k_scan3(const int* __restrict__ deg, const int* __restrict__ bsum,
                        int* __restrict__ rowptr, int n){
  __shared__ int wtot[4];
  int tid = threadIdx.x, lane = tid & 63, wid = tid >> 6;
  int base = blockIdx.x * SCHUNK + tid * 8;
  int l[8];
  int acc = 0;
  #pragma unroll
  for (int j = 0; j < 8; ++j){
    int i = base + j;
    acc += (i < n) ? deg[i] : 0;
    l[j] = acc;
  }
  int v = acc;
  #pragma unroll
  for (int off = 1; off < 64; off <<= 1){
    int u = __shfl_up(v, off);
    if (lane >= off) v += u;
  }
  if (lane == 63) wtot[wid] = v;
  __syncthreads();
  int woff = 0;
  for (int w = 0; w < wid; ++w) woff += wtot[w];
  int boff = (blockIdx.x == 0) ? 0 : bsum[blockIdx.x - 1];
  int tpre = boff + woff + (v - acc);
  #pragma unroll
  for (int j = 0; j < 8; ++j){
    int i = base + j;
    if (i < n) rowptr[i + 1] = tpre + l[j];
  }
  if (blockIdx.x == 0 && tid == 0) rowptr[0] = 0;
}

__global__ void k_fill(const int* __restrict__ row, const int* __restrict__ col,
                       const int* __restrict__ rowptr, int* __restrict__ cursor,
                       int* __restrict__ cols_s, int E){
  int i = blockIdx.x * blockDim.x + threadIdx.x;
  if (i < E){
    int r = row[i];
    int p = atomicAdd(&cursor[r], 1);
    cols_s[rowptr[r] + p] = col[i];
  }
}

// ---------------- neighbor mean (LDS-staged cols, unrolled gather) ----------------
__global__ void k_nmean(const float* __restrict__ x, const int* __restrict__ rowptr,
                        const int* __restrict__ cols, float* __restrict__ nmean, int n){
  __shared__ int s_cv[4][64];
  int wid = threadIdx.x >> 6;
  int node = blockIdx.x * 4 + wid;
  if (node >= n) return;
  int lane = threadIdx.x & 63;
  int s = rowptr[node], e = rowptr[node + 1];
  float acc = 0.f;
  for (int j0 = s; j0 < e; j0 += 64){
    int len = min(64, e - j0);
    int cv = (lane < len) ? cols[j0 + lane] : 0;
    s_cv[wid][lane] = cv;
    int k = 0;
    for (; k + 4 <= len; k += 4){
      int c0 = s_cv[wid][k], c1 = s_cv[wid][k+1], c2 = s_cv[wid][k+2], c3 = s_cv[wid][k+3];
      if (lane < DIN){
        float v0 = x[c0 * DIN + lane], v1 = x[c1 * DIN + lane];
        float v2 = x[c2 * DIN + lane], v3 = x[c3 * DIN + lane];
        acc += (v0 + v1) + (v2 + v3);
      }
    }
    for (; k < len; ++k){
      int c = s_cv[wid][k];
      if (lane < DIN) acc += x[c * DIN + lane];
    }
  }
  if (lane < DIN){
    float d = (float)(e - s);
    nmean[node * DIN + lane] = acc / (d + 1e-8f);
  }
}

// ---------------- input projection: one wave per node, shfl-broadcast x ----------------
__global__ void k_h_in(const float* __restrict__ x, const float* __restrict__ nmean,
                       const float* __restrict__ Win, const float* __restrict__ bin,
                       const float* __restrict__ Wagg, const float* __restrict__ bagg,
                       float* __restrict__ out, int n){
  int wid = threadIdx.x >> 6;
  int node = blockIdx.x * 4 + wid;
  if (node >= n) return;
  int lane = threadIdx.x & 63;
  float xv = 0.f;
  if (lane < DIN) xv = x[node * DIN + lane];
  else if (lane < 2 * DIN) xv = nmean[node * DIN + (lane - DIN)];
  float acc0 = bin[lane]      + bagg[lane];
  float acc1 = bin[64 + lane] + bagg[64 + lane];
  #pragma unroll
  for (int d = 0; d < DIN; ++d){
    float xd = __shfl(xv, d);
    float nd = __shfl(xv, DIN + d);
    acc0 += xd * Win[d * HID + lane]       + nd * Wagg[d * HID + lane];
    acc1 += xd * Win[d * HID + 64 + lane]  + nd * Wagg[d * HID + 64 + lane];
  }
  out[node * HID + lane]      = acc0;
  out[node * HID + 64 + lane] = acc1;
}

// ---------------- weight prep: f32 [d][c] -> bf16 [c][d] ----------------
__global__ void k_wt_sh(const float* __restrict__ W, ushort_t* __restrict__ Wt){
  int i = blockIdx.x * 256 + threadIdx.x;
  int c = i >> 7, d = i & 127;
  Wt[c * HID + d] = f2bf(W[d * HID + c]);
}
// mh_Wv [4][128][32] -> bf16 [c][d], c = h*32+e
__global__ void k_wt_mh(const float* __restrict__ mhWv, ushort_t* __restrict__ Wt){
  int i = blockIdx.x * 256 + threadIdx.x;
  int c = i >> 7, d = i & 127;
  Wt[c * HID + d] = f2bf(mhWv[((c >> 5) * HID + d) * 32 + (c & 31)]);
}

// ---------------- MFMA GEMM: C[n][128] = A[n][128] @ Wt^T + bias ----------------
// A: f32 row-major (converted to bf16 frags in-kernel). Wt: bf16 [col][k].
// mode 2: bf16 out to dstb ; mode 1: leaky f32 out to dstf
__global__ void k_gemm_mfma(const float* __restrict__ A, const ushort_t* __restrict__ Bt,
                            const float* __restrict__ bias, ushort_t* __restrict__ dstb,
                            float* __restrict__ dstf, int n, int mode){
  int wv = threadIdx.x >> 6, lane = threadIdx.x & 63;
  int r0 = blockIdx.x * 64 + wv * 16;
  int lr = lane & 15, lk = lane >> 4;
  // A fragments: row r0+lr, k = lk*8 + kb*32 + [0..7]
  int arow = r0 + lr; if (arow >= n) arow = n - 1;
  const float* Ap = A + (size_t)arow * HID + lk * 8;
  bf16x8 a[4];
  #pragma unroll
  for (int kb = 0; kb < 4; ++kb){
    float4 lo = *(const float4*)(Ap + kb * 32);
    float4 hi = *(const float4*)(Ap + kb * 32 + 4);
    bf16x8 t;
    t[0] = (short)f2bf(lo.x); t[1] = (short)f2bf(lo.y);
    t[2] = (short)f2bf(lo.z); t[3] = (short)f2bf(lo.w);
    t[4] = (short)f2bf(hi.x); t[5] = (short)f2bf(hi.y);
    t[6] = (short)f2bf(hi.z); t[7] = (short)f2bf(hi.w);
    a[kb] = t;
  }
  f32x4 acc[8];
  #pragma unroll
  for (int t = 0; t < 8; ++t) acc[t] = (f32x4){0.f, 0.f, 0.f, 0.f};
  #pragma unroll
  for (int t = 0; t < 8; ++t){
    const ushort_t* Bp = Bt + (size_t)(t * 16 + lr) * HID + lk * 8;
    #pragma unroll
    for (int kb = 0; kb < 4; ++kb){
      bf16x8 b = *(const bf16x8*)(Bp + kb * 32);
      acc[t] = __builtin_amdgcn_mfma_f32_16x16x32_bf16(a[kb], b, acc[t], 0, 0, 0);
    }
  }
  // epilogue: C[r0 + lk*4 + j][t*16 + lr]
  #pragma unroll
  for (int t = 0; t < 8; ++t){
    int col = t * 16 + lr;
    float bs = bias[col];
    #pragma unroll
    for (int j = 0; j < 4; ++j){
      int rr = r0 + lk * 4 + j;
      if (rr < n){
        float v = acc[t][j] + bs;
        if (mode == 2) dstb[(size_t)rr * HID + col] = f2bf(v);
        else           dstf[(size_t)rr * HID + col] = leaky(v);
      }
    }
  }
}

// ---------------- single-head scores ----------------
__global__ void k_scores_sh(const float* __restrict__ h, const float* __restrict__ asrc,
                            const float* __restrict__ adst,
                            float* __restrict__ ssrc, float* __restrict__ sdst, int n){
  int node = blockIdx.x * 4 + (threadIdx.x >> 6);
  if (node >= n) return;
  int lane = threadIdx.x & 63;
  float h0 = h[node * HID + lane], h1 = h[node * HID + 64 + lane];
  float ps = h0 * asrc[lane] + h1 * asrc[64 + lane];
  float pd = h0 * adst[lane] + h1 * adst[64 + lane];
  ps = wred_sum(ps);
  pd = wred_sum(pd);
  if (lane == 0){ ssrc[node] = ps; sdst[node] = pd; }
}

// ---------------- multi-head scores ----------------
__global__ void k_scores_mh(const float* __restrict__ h, const float* __restrict__ asrc,
                            const float* __restrict__ adst,
                            float* __restrict__ ssrc, float* __restrict__ sdst, int n){
  int node = blockIdx.x * 4 + (threadIdx.x >> 6);
  if (node >= n) return;
  int lane = threadIdx.x & 63;
  float h0 = h[node * HID + lane], h1 = h[node * HID + 64 + lane];
  #pragma unroll
  for (int hd = 0; hd < 4; ++hd){
    float ps = h0 * asrc[hd * HID + lane] + h1 * asrc[hd * HID + 64 + lane];
    float pd = h0 * adst[hd * HID + lane] + h1 * adst[hd * HID + 64 + lane];
    ps = wred_sum(ps);
    pd = wred_sum(pd);
    if (lane == 0){ ssrc[node * 4 + hd] = ps; sdst[node * 4 + hd] = pd; }
  }
}

// ---------------- single-head aggregation: no-max softmax, LDS-staged, bf16 V ----------------
__global__ void k_agg_sh(const int* __restrict__ rowptr, const int* __restrict__ cols,
                         const float* __restrict__ ssrc, const float* __restrict__ sdst,
                         const ushort_t* __restrict__ hv, const float* __restrict__ resid,
                         const float* __restrict__ bng, const float* __restrict__ bnb,
                         const float* __restrict__ bnm, const float* __restrict__ bnv,
                         float* __restrict__ out, int n){
  __shared__ int   s_cv[4][64];
  __shared__ float s_ex[4][64];
  int wid = threadIdx.x >> 6;
  int node = blockIdx.x * 4 + wid;
  if (node >= n) return;
  int lane = threadIdx.x & 63;
  const unsigned* hv32 = (const unsigned*)hv;
  int s = rowptr[node], e = rowptr[node + 1];
  float sq = ssrc[node];
  float ssum = 0.f, a0 = 0.f, a1 = 0.f;
  for (int j0 = s; j0 < e; j0 += 64){
    int len = min(64, e - j0);
    int cv = 0; float ex = 0.f;
    if (lane < len){
      cv = cols[j0 + lane];
      ex = __expf(leaky(sq + sdst[cv]));
    }
    ssum += ex;
    s_cv[wid][lane] = cv;
    s_ex[wid][lane] = ex;
    int k = 0;
    for (; k + 4 <= len; k += 4){
      int c0 = s_cv[wid][k],   c1 = s_cv[wid][k+1];
      int c2 = s_cv[wid][k+2], c3 = s_cv[wid][k+3];
      float l0 = s_ex[wid][k],   l1 = s_ex[wid][k+1];
      float l2 = s_ex[wid][k+2], l3 = s_ex[wid][k+3];
      unsigned p0 = hv32[c0 * 64 + lane], p1 = hv32[c1 * 64 + lane];
      unsigned p2 = hv32[c2 * 64 + lane], p3 = hv32[c3 * 64 + lane];
      a0 += l0 * bf_lo(p0); a1 += l0 * bf_hi(p0);
      a0 += l1 * bf_lo(p1); a1 += l1 * bf_hi(p1);
      a0 += l2 * bf_lo(p2); a1 += l2 * bf_hi(p2);
      a0 += l3 * bf_lo(p3); a1 += l3 * bf_hi(p3);
    }
    for (; k < len; ++k){
      int c = s_cv[wid][k];
      float l = s_ex[wid][k];
      unsigned p = hv32[c * 64 + lane];
      a0 += l * bf_lo(p); a1 += l * bf_hi(p);
    }
  }
  ssum = wred_sum(ssum);
  float inv = 1.f / (ssum + 1e-16f);
  a0 *= inv; a1 *= inv;
  int d0 = 2 * lane, d1 = 2 * lane + 1;
  float v0 = (a0 - bnm[d0]) * rsqrtf(bnv[d0] + BN_EPS) * bng[d0] + bnb[d0];
  float v1 = (a1 - bnm[d1]) * rsqrtf(bnv[d1] + BN_EPS) * bng[d1] + bnb[d1];
  if (resid){ v0 += resid[node * HID + d0]; v1 += resid[node * HID + d1]; }
  out[node * HID + d0] = leaky(v0);
  out[node * HID + d1] = leaky(v1);
}

// ---------------- multi-head aggregation: no-max softmax, LDS-staged, bf16 V ----------------
__global__ void k_agg_mh(const int* __restrict__ rowptr, const int* __restrict__ cols,
                         const float* __restrict__ ssrc, const float* __restrict__ sdst,
                         const ushort_t* __restrict__ hv,
                         const float* __restrict__ bng, const float* __restrict__ bnb,
                         const float* __restrict__ bnm, const float* __restrict__ bnv,
                         float* __restrict__ out, int n){
  __shared__ int    s_cv[4][64];
  __shared__ float4 s_ex[4][64];
  int wid = threadIdx.x >> 6;
  int node = blockIdx.x * 4 + wid;
  if (node >= n) return;
  int lane = threadIdx.x & 63;
  const unsigned* hv32 = (const unsigned*)hv;
  int s = rowptr[node], e = rowptr[node + 1];
  const float4 sq = *(const float4*)&ssrc[node * 4];
  int hd = lane >> 4;
  float s0 = 0.f, s1 = 0.f, s2 = 0.f, s3 = 0.f;
  float a0 = 0.f, a1 = 0.f;
  const float* exw = &s_ex[wid][0].x;
  for (int j0 = s; j0 < e; j0 += 64){
    int len = min(64, e - j0);
    int cv = 0;
    float e0 = 0.f, e1 = 0.f, e2 = 0.f, e3 = 0.f;
    if (lane < len){
      cv = cols[j0 + lane];
      float4 kd = *(const float4*)&sdst[cv * 4];
      e0 = __expf(leaky(sq.x + kd.x)); e1 = __expf(leaky(sq.y + kd.y));
      e2 = __expf(leaky(sq.z + kd.z)); e3 = __expf(leaky(sq.w + kd.w));
    }
    s0 += e0; s1 += e1; s2 += e2; s3 += e3;
    s_cv[wid][lane] = cv;
    s_ex[wid][lane] = make_float4(e0, e1, e2, e3);
    int k = 0;
    for (; k + 4 <= len; k += 4){
      int c0 = s_cv[wid][k],   c1 = s_cv[wid][k+1];
      int c2 = s_cv[wid][k+2], c3 = s_cv[wid][k+3];
      float l0 = exw[(k)   * 4 + hd], l1 = exw[(k+1) * 4 + hd];
      float l2 = exw[(k+2) * 4 + hd], l3 = exw[(k+3) * 4 + hd];
      unsigned p0 = hv32[c0 * 64 + lane], p1 = hv32[c1 * 64 + lane];
      unsigned p2 = hv32[c2 * 64 + lane], p3 = hv32[c3 * 64 + lane];
      a0 += l0 * bf_lo(p0); a1 += l0 * bf_hi(p0);
      a0 += l1 * bf_lo(p1); a1 += l1 * bf_hi(p1);
      a0 += l2 * bf_lo(p2); a1 += l2 * bf_hi(p2);
      a0 += l3 * bf_lo(p3); a1 += l3 * bf_hi(p3);
    }
    for (; k < len; ++k){
      int c = s_cv[wid][k];
      float l = exw[k * 4 + hd];
      unsigned p = hv32[c * 64 + lane];
      a0 += l * bf_lo(p); a1 += l * bf_hi(p);
    }
  }
  s0 = wred_sum(s0); s1 = wred_sum(s1);
  s2 = wred_sum(s2); s3 = wred_sum(s3);
  float i0 = 1.f / (s0 + 1e-16f), i1 = 1.f / (s1 + 1e-16f);
  float i2 = 1.f / (s2 + 1e-16f), i3 = 1.f / (s3 + 1e-16f);
  float ih = sel4(i0, i1, i2, i3, hd);
  a0 *= ih; a1 *= ih;
  int d0 = 2 * lane, d1 = 2 * lane + 1;
  float v0 = (a0 - bnm[d0]) * rsqrtf(bnv[d0] + BN_EPS) * bng[d0] + bnb[d0];
  float v1 = (a1 - bnm[d1]) * rsqrtf(bnv[d1] + BN_EPS) * bng[d1] + bnb[d1];
  out[node * HID + d0] = leaky(v0);
  out[node * HID + d1] = leaky(v1);
}

// ---------------- output head ----------------
__global__ void k_out(const float* __restrict__ o1, const float* __restrict__ Wo2,
                      const float* __restrict__ bo2, const float* __restrict__ x,
                      float* __restrict__ out, int n){
  int node = blockIdx.x * 4 + (threadIdx.x >> 6);
  if (node >= n) return;
  int lane = threadIdx.x & 63;
  float a = o1[node * HID + lane], b = o1[node * HID + 64 + lane];
  float p0 = a * Wo2[lane * 3 + 0] + b * Wo2[(lane + 64) * 3 + 0];
  float p1 = a * Wo2[lane * 3 + 1] + b * Wo2[(lane + 64) * 3 + 1];
  float p2 = a * Wo2[lane * 3 + 2] + b * Wo2[(lane + 64) * 3 + 2];
  p0 = wred_sum(p0); p1 = wred_sum(p1); p2 = wred_sum(p2);
  if (lane == 0){
    out[node * 3 + 0] = x[node * DIN + 15] + p0 + bo2[0];
    out[node * 3 + 1] = x[node * DIN + 16] + p1 + bo2[1];
    out[node * 3 + 2] = x[node * DIN + 17] + p2 + bo2[2];
  }
}

extern "C" void kernel_launch(void* const* d_in, const int* in_sizes, int n_in,
                              void* d_out, int out_size, void* d_ws, size_t ws_size,
                              hipStream_t stream){
  const float* x       = (const float*)d_in[0];
  const int*   ei      = (const int*)  d_in[1];
  const float* W_in    = (const float*)d_in[2];
  const float* b_in    = (const float*)d_in[3];
  const float* W_agg   = (const float*)d_in[4];
  const float* b_agg   = (const float*)d_in[5];
  const float* sh_Wv   = (const float*)d_in[6];
  const float* sh_b    = (const float*)d_in[7];
  const float* sh_asrc = (const float*)d_in[8];
  const float* sh_adst = (const float*)d_in[9];
  const float* mh_Wv   = (const float*)d_in[10];
  const float* mh_b    = (const float*)d_in[11];
  const float* mh_asrc = (const float*)d_in[12];
  const float* mh_adst = (const float*)d_in[13];
  const float* bn_g    = (const float*)d_in[14];
  const float* bn_bt   = (const float*)d_in[15];
  const float* bn_m    = (const float*)d_in[16];
  const float* bn_v    = (const float*)d_in[17];
  const float* W_o1    = (const float*)d_in[18];
  const float* b_o1    = (const float*)d_in[19];
  const float* W_o2    = (const float*)d_in[20];
  const float* b_o2    = (const float*)d_in[21];
  float* out = (float*)d_out;

  const int N = in_sizes[0] / DIN;
  const int E = in_sizes[1] / 2;
  const int* row = ei;
  const int* col = ei + E;

  char* w = (char*)d_ws;
  size_t off = 0;
  auto alloc = [&](size_t bytes) -> void* {
    void* p = w + off;
    off = (off + bytes + 255) & ~(size_t)255;
    return p;
  };
  int*      tmp    = (int*)     alloc((size_t)N * 4);
  int*      rowptr = (int*)     alloc((size_t)(N + 1) * 4);
  int*      cols_s = (int*)     alloc((size_t)E * 4);
  int*      bsum   = (int*)     alloc((size_t)1024 * 4);
  float*    nmean  = (float*)   alloc((size_t)N * DIN * 4);
  float*    ssrc   = (float*)   alloc((size_t)N * 4 * 4);
  float*    sdst   = (float*)   alloc((size_t)N * 4 * 4);
  ushort_t* wt0    = (ushort_t*)alloc((size_t)HID * HID * 2);
  ushort_t* wt1    = (ushort_t*)alloc((size_t)HID * HID * 2);
  ushort_t* wt2    = (ushort_t*)alloc((size_t)HID * HID * 2);
  ushort_t* wt3    = (ushort_t*)alloc((size_t)HID * HID * 2);
  float*    buf0   = (float*)   alloc((size_t)N * HID * 4);
  float*    buf1   = (float*)   alloc((size_t)N * HID * 4);
  float*    buf2   = (float*)   alloc((size_t)N * HID * 4);
  ushort_t* hvb    = (ushort_t*)alloc((size_t)N * HID * 2);

  const int eb = (E + 255) / 256;
  const int nb4 = (N + 3) / 4;
  const int gb = (N + 63) / 64;
  const int nsb = (N + SCHUNK - 1) / SCHUNK;

  // CSR build
  hipMemsetAsync(tmp, 0, (size_t)N * 4, stream);
  k_deg<<<eb, 256, 0, stream>>>(row, tmp, E);
  k_scan1<<<nsb, 256, 0, stream>>>(tmp, bsum, N);
  k_scan2<<<1, 64, 0, stream>>>(bsum, nsb);
  k_scan3<<<nsb, 256, 0, stream>>>(tmp, bsum, rowptr, N);
  hipMemsetAsync(tmp, 0, (size_t)N * 4, stream);
  k_fill<<<eb, 256, 0, stream>>>(row, col, rowptr, tmp, cols_s, E);

  // weight prep (bf16, transposed)
  k_wt_sh<<<64, 256, 0, stream>>>(sh_Wv, wt0);
  k_wt_mh<<<64, 256, 0, stream>>>(mh_Wv, wt1);
  k_wt_sh<<<64, 256, 0, stream>>>(sh_Wv + HID * HID, wt2);
  k_wt_sh<<<64, 256, 0, stream>>>(W_o1, wt3);

  // neighbor mean + input projection -> buf0 (= x0 = h)
  k_nmean<<<nb4, 256, 0, stream>>>(x, rowptr, cols_s, nmean, N);
  k_h_in<<<nb4, 256, 0, stream>>>(x, nmean, W_in, b_in, W_agg, b_agg, buf0, N);

  // layer 0: single-head (params [0]), residual = x0(buf0), bn[0] -> buf1
  k_gemm_mfma<<<gb, 256, 0, stream>>>(buf0, wt0, sh_b, hvb, nullptr, N, 2);
  k_scores_sh<<<nb4, 256, 0, stream>>>(buf0, sh_asrc, sh_adst, ssrc, sdst, N);
  k_agg_sh<<<nb4, 256, 0, stream>>>(rowptr, cols_s, ssrc, sdst, hvb, buf0,
                                    bn_g, bn_bt, bn_m, bn_v, buf1, N);

  // layer 1: multi-head, bn[1], no residual -> buf0
  k_gemm_mfma<<<gb, 256, 0, stream>>>(buf1, wt1, mh_b, hvb, nullptr, N, 2);
  k_scores_mh<<<nb4, 256, 0, stream>>>(buf1, mh_asrc, mh_adst, ssrc, sdst, N);
  k_agg_mh<<<nb4, 256, 0, stream>>>(rowptr, cols_s, ssrc, sdst, hvb,
                                    bn_g + HID, bn_bt + HID, bn_m + HID, bn_v + HID, buf0, N);

  // layer 2: single-head (params [1]), residual = buf0, bn[2] -> buf1
  k_gemm_mfma<<<gb, 256, 0, stream>>>(buf0, wt2, sh_b + HID, hvb, nullptr, N, 2);
  k_scores_sh<<<nb4, 256, 0, stream>>>(buf0, sh_asrc + HID, sh_adst + HID, ssrc, sdst, N);
  k_agg_sh<<<nb4, 256, 0, stream>>>(rowptr, cols_s, ssrc, sdst, hvb, buf0,
                                    bn_g + 2 * HID, bn_bt + 2 * HID, bn_m + 2 * HID, bn_v + 2 * HID,
                                    buf1, N);

  // output head
  k_gemm_mfma<<<gb, 256, 0, stream>>>(buf1, wt3, b_o1, nullptr, buf2, N, 1);
  k_out<<<nb4, 256, 0, stream>>>(buf2, W_o2, b_o2, x, out, N);
}

// Round 8
// 380.873 us; speedup vs baseline: 2.2461x; 1.1412x over previous
//
#include <hip/hip_runtime.h>
#include <math.h>

#define DIN 18
#define HID 128
#define NEGS 0.2f
#define BN_EPS 1e-5f
#define SCHUNK 2048

typedef unsigned short ushort_t;
typedef __attribute__((ext_vector_type(8))) short bf16x8;
typedef __attribute__((ext_vector_type(4))) float f32x4;

__device__ __forceinline__ float leaky(float x){ return x >= 0.f ? x : NEGS * x; }

__device__ __forceinline__ float wred_sum(float v){
  #pragma unroll
  for (int off = 32; off; off >>= 1) v += __shfl_xor(v, off);
  return v;
}

__device__ __forceinline__ ushort_t f2bf(float f){
  union { float f; unsigned u; } v; v.f = f;
  unsigned r = v.u + 0x7FFFu + ((v.u >> 16) & 1u);
  return (ushort_t)(r >> 16);
}
__device__ __forceinline__ float bf_lo(unsigned p){ return __uint_as_float(p << 16); }
__device__ __forceinline__ float bf_hi(unsigned p){ return __uint_as_float(p & 0xFFFF0000u); }

__device__ __forceinline__ float sel4(float v0, float v1, float v2, float v3, int hd){
  float a = (hd & 1) ? v1 : v0;
  float b = (hd & 1) ? v3 : v2;
  return (hd & 2) ? b : a;
}

// ---------------- CSR build: single atomic pass ----------------
__global__ void k_deg_rank(const int* __restrict__ row, int* __restrict__ deg,
                           int* __restrict__ rank, int E){
  int i = blockIdx.x * blockDim.x + threadIdx.x;
  if (i < E) rank[i] = atomicAdd(&deg[row[i]], 1);
}

__global__ void k_scan1(const int* __restrict__ deg, int* __restrict__ bsum, int n){
  __shared__ int wtot[4];
  int tid = threadIdx.x, lane = tid & 63, wid = tid >> 6;
  int base = blockIdx.x * SCHUNK + tid * 8;
  int acc = 0;
  #pragma unroll
  for (int j = 0; j < 8; ++j){
    int i = base + j;
    if (i < n) acc += deg[i];
  }
  #pragma unroll
  for (int off = 32; off; off >>= 1) acc += __shfl_xor(acc, off);
  if (lane == 0) wtot[wid] = acc;
  __syncthreads();
  if (tid == 0) bsum[blockIdx.x] = wtot[0] + wtot[1] + wtot[2] + wtot[3];
}

__global__ void k_scan2(int* __restrict__ bsum, int nb){
  int lane = threadIdx.x;
  int carry = 0;
  for (int base = 0; base < nb; base += 64){
    int i = base + lane;
    int v = (i < nb) ? bsum[i] : 0;
    #pragma unroll
    for (int off = 1; off < 64; off <<= 1){
      int u = __shfl_up(v, off);
      if (lane >= off) v += u;
    }
    if (i < nb) bsum[i] = v + carry;
    carry += __shfl(v, 63);
  }
}

__global__ void k_scan3(const int* __restrict__ deg, const int* __restrict__ bsum,
                        int* __restrict__ rowptr, int n){
  __shared__ int wtot[4];
  int tid = threadIdx.x, lane = tid & 63, wid = tid >> 6;
  int base = blockIdx.x * SCHUNK + tid * 8;
  int l[8];
  int acc = 0;
  #pragma unroll
  for (int j = 0; j < 8; ++j){
    int i = base + j;
    acc += (i < n) ? deg[i] : 0;
    l[j] = acc;
  }
  int v = acc;
  #pragma unroll
  for (int off = 1; off < 64; off <<= 1){
    int u = __shfl_up(v, off);
    if (lane >= off) v += u;
  }
  if (lane == 63) wtot[wid] = v;
  __syncthreads();
  int woff = 0;
  for (int w = 0; w < wid; ++w) woff += wtot[w];
  int boff = (blockIdx.x == 0) ? 0 : bsum[blockIdx.x - 1];
  int tpre = boff + woff + (v - acc);
  #pragma unroll
  for (int j = 0; j < 8; ++j){
    int i = base + j;
    if (i < n) rowptr[i + 1] = tpre + l[j];
  }
  if (blockIdx.x == 0 && tid == 0) rowptr[0] = 0;
}

__global__ void k_scatter(const int* __restrict__ row, const int* __restrict__ col,
                          const int* __restrict__ rowptr, const int* __restrict__ rank,
                          int* __restrict__ cols_s, int E){
  int i = blockIdx.x * blockDim.x + threadIdx.x;
  if (i < E){
    cols_s[rowptr[row[i]] + rank[i]] = col[i];
  }
}

// ---------------- neighbor mean (LDS-staged cols, unrolled gather) ----------------
__global__ void k_nmean(const float* __restrict__ x, const int* __restrict__ rowptr,
                        const int* __restrict__ cols, float* __restrict__ nmean, int n){
  __shared__ int s_cv[4][64];
  int wid = threadIdx.x >> 6;
  int node = blockIdx.x * 4 + wid;
  if (node >= n) return;
  int lane = threadIdx.x & 63;
  int s = rowptr[node], e = rowptr[node + 1];
  float acc = 0.f;
  for (int j0 = s; j0 < e; j0 += 64){
    int len = min(64, e - j0);
    int cv = (lane < len) ? cols[j0 + lane] : 0;
    s_cv[wid][lane] = cv;
    int k = 0;
    for (; k + 4 <= len; k += 4){
      int c0 = s_cv[wid][k], c1 = s_cv[wid][k+1], c2 = s_cv[wid][k+2], c3 = s_cv[wid][k+3];
      if (lane < DIN){
        float v0 = x[c0 * DIN + lane], v1 = x[c1 * DIN + lane];
        float v2 = x[c2 * DIN + lane], v3 = x[c3 * DIN + lane];
        acc += (v0 + v1) + (v2 + v3);
      }
    }
    for (; k < len; ++k){
      int c = s_cv[wid][k];
      if (lane < DIN) acc += x[c * DIN + lane];
    }
  }
  if (lane < DIN){
    float d = (float)(e - s);
    nmean[node * DIN + lane] = acc / (d + 1e-8f);
  }
}

// ---------------- input projection + fused layer-0 single-head scores ----------------
__global__ void k_h_in(const float* __restrict__ x, const float* __restrict__ nmean,
                       const float* __restrict__ Win, const float* __restrict__ bin,
                       const float* __restrict__ Wagg, const float* __restrict__ bagg,
                       const float* __restrict__ asrc, const float* __restrict__ adst,
                       float* __restrict__ ssrc, float* __restrict__ sdst,
                       float* __restrict__ out, int n){
  int wid = threadIdx.x >> 6;
  int node = blockIdx.x * 4 + wid;
  if (node >= n) return;
  int lane = threadIdx.x & 63;
  float xv = 0.f;
  if (lane < DIN) xv = x[node * DIN + lane];
  else if (lane < 2 * DIN) xv = nmean[node * DIN + (lane - DIN)];
  float acc0 = bin[lane]      + bagg[lane];
  float acc1 = bin[64 + lane] + bagg[64 + lane];
  #pragma unroll
  for (int d = 0; d < DIN; ++d){
    float xd = __shfl(xv, d);
    float nd = __shfl(xv, DIN + d);
    acc0 += xd * Win[d * HID + lane]       + nd * Wagg[d * HID + lane];
    acc1 += xd * Win[d * HID + 64 + lane]  + nd * Wagg[d * HID + 64 + lane];
  }
  out[node * HID + lane]      = acc0;
  out[node * HID + 64 + lane] = acc1;
  float ps = acc0 * asrc[lane] + acc1 * asrc[64 + lane];
  float pd = acc0 * adst[lane] + acc1 * adst[64 + lane];
  ps = wred_sum(ps);
  pd = wred_sum(pd);
  if (lane == 0){ ssrc[node] = ps; sdst[node] = pd; }
}

// ---------------- weight prep: f32 [d][c] -> bf16 [c][d] ----------------
__global__ void k_wt_sh(const float* __restrict__ W, ushort_t* __restrict__ Wt){
  int i = blockIdx.x * 256 + threadIdx.x;
  int c = i >> 7, d = i & 127;
  Wt[c * HID + d] = f2bf(W[d * HID + c]);
}
__global__ void k_wt_mh(const float* __restrict__ mhWv, ushort_t* __restrict__ Wt){
  int i = blockIdx.x * 256 + threadIdx.x;
  int c = i >> 7, d = i & 127;
  Wt[c * HID + d] = f2bf(mhWv[((c >> 5) * HID + d) * 32 + (c & 31)]);
}

// ---------------- MFMA GEMM ----------------
__global__ void k_gemm_mfma(const float* __restrict__ A, const ushort_t* __restrict__ Bt,
                            const float* __restrict__ bias, ushort_t* __restrict__ dstb,
                            float* __restrict__ dstf, int n, int mode){
  int wv = threadIdx.x >> 6, lane = threadIdx.x & 63;
  int r0 = blockIdx.x * 64 + wv * 16;
  int lr = lane & 15, lk = lane >> 4;
  int arow = r0 + lr; if (arow >= n) arow = n - 1;
  const float* Ap = A + (size_t)arow * HID + lk * 8;
  bf16x8 a[4];
  #pragma unroll
  for (int kb = 0; kb < 4; ++kb){
    float4 lo = *(const float4*)(Ap + kb * 32);
    float4 hi = *(const float4*)(Ap + kb * 32 + 4);
    bf16x8 t;
    t[0] = (short)f2bf(lo.x); t[1] = (short)f2bf(lo.y);
    t[2] = (short)f2bf(lo.z); t[3] = (short)f2bf(lo.w);
    t[4] = (short)f2bf(hi.x); t[5] = (short)f2bf(hi.y);
    t[6] = (short)f2bf(hi.z); t[7] = (short)f2bf(hi.w);
    a[kb] = t;
  }
  f32x4 acc[8];
  #pragma unroll
  for (int t = 0; t < 8; ++t) acc[t] = (f32x4){0.f, 0.f, 0.f, 0.f};
  #pragma unroll
  for (int t = 0; t < 8; ++t){
    const ushort_t* Bp = Bt + (size_t)(t * 16 + lr) * HID + lk * 8;
    #pragma unroll
    for (int kb = 0; kb < 4; ++kb){
      bf16x8 b = *(const bf16x8*)(Bp + kb * 32);
      acc[t] = __builtin_amdgcn_mfma_f32_16x16x32_bf16(a[kb], b, acc[t], 0, 0, 0);
    }
  }
  #pragma unroll
  for (int t = 0; t < 8; ++t){
    int col = t * 16 + lr;
    float bs = bias[col];
    #pragma unroll
    for (int j = 0; j < 4; ++j){
      int rr = r0 + lk * 4 + j;
      if (rr < n){
        float v = acc[t][j] + bs;
        if (mode == 2) dstb[(size_t)rr * HID + col] = f2bf(v);
        else           dstf[(size_t)rr * HID + col] = leaky(v);
      }
    }
  }
}

// ---------------- single-head aggregation + optional fused mh scores ----------------
__global__ void k_agg_sh(const int* __restrict__ rowptr, const int* __restrict__ cols,
                         const float* __restrict__ ssrc, const float* __restrict__ sdst,
                         const ushort_t* __restrict__ hv, const float* __restrict__ resid,
                         const float* __restrict__ bng, const float* __restrict__ bnb,
                         const float* __restrict__ bnm, const float* __restrict__ bnv,
                         const float* __restrict__ masrc, const float* __restrict__ madst,
                         float* __restrict__ ossrc, float* __restrict__ osdst,
                         float* __restrict__ out, int n){
  __shared__ int   s_cv[4][64];
  __shared__ float s_ex[4][64];
  int wid = threadIdx.x >> 6;
  int node = blockIdx.x * 4 + wid;
  if (node >= n) return;
  int lane = threadIdx.x & 63;
  const unsigned* hv32 = (const unsigned*)hv;
  int s = rowptr[node], e = rowptr[node + 1];
  float sq = ssrc[node];
  float ssum = 0.f, a0 = 0.f, a1 = 0.f;
  for (int j0 = s; j0 < e; j0 += 64){
    int len = min(64, e - j0);
    int cv = 0; float ex = 0.f;
    if (lane < len){
      cv = cols[j0 + lane];
      ex = __expf(leaky(sq + sdst[cv]));
    }
    ssum += ex;
    s_cv[wid][lane] = cv;
    s_ex[wid][lane] = ex;
    int k = 0;
    for (; k + 4 <= len; k += 4){
      int c0 = s_cv[wid][k],   c1 = s_cv[wid][k+1];
      int c2 = s_cv[wid][k+2], c3 = s_cv[wid][k+3];
      float l0 = s_ex[wid][k],   l1 = s_ex[wid][k+1];
      float l2 = s_ex[wid][k+2], l3 = s_ex[wid][k+3];
      unsigned p0 = hv32[c0 * 64 + lane], p1 = hv32[c1 * 64 + lane];
      unsigned p2 = hv32[c2 * 64 + lane], p3 = hv32[c3 * 64 + lane];
      a0 += l0 * bf_lo(p0); a1 += l0 * bf_hi(p0);
      a0 += l1 * bf_lo(p1); a1 += l1 * bf_hi(p1);
      a0 += l2 * bf_lo(p2); a1 += l2 * bf_hi(p2);
      a0 += l3 * bf_lo(p3); a1 += l3 * bf_hi(p3);
    }
    for (; k < len; ++k){
      int c = s_cv[wid][k];
      float l = s_ex[wid][k];
      unsigned p = hv32[c * 64 + lane];
      a0 += l * bf_lo(p); a1 += l * bf_hi(p);
    }
  }
  ssum = wred_sum(ssum);
  float inv = 1.f / (ssum + 1e-16f);
  a0 *= inv; a1 *= inv;
  int d0 = 2 * lane, d1 = 2 * lane + 1;
  float v0 = (a0 - bnm[d0]) * rsqrtf(bnv[d0] + BN_EPS) * bng[d0] + bnb[d0];
  float v1 = (a1 - bnm[d1]) * rsqrtf(bnv[d1] + BN_EPS) * bng[d1] + bnb[d1];
  if (resid){ v0 += resid[node * HID + d0]; v1 += resid[node * HID + d1]; }
  float o0 = leaky(v0), o1 = leaky(v1);
  out[node * HID + d0] = o0;
  out[node * HID + d1] = o1;
  if (ossrc){
    #pragma unroll
    for (int h = 0; h < 4; ++h){
      float ps = o0 * masrc[h * HID + d0] + o1 * masrc[h * HID + d1];
      float pd = o0 * madst[h * HID + d0] + o1 * madst[h * HID + d1];
      ps = wred_sum(ps);
      pd = wred_sum(pd);
      if (lane == 0){ ossrc[node * 4 + h] = ps; osdst[node * 4 + h] = pd; }
    }
  }
}

// ---------------- multi-head aggregation + fused layer-2 sh scores ----------------
__global__ void k_agg_mh(const int* __restrict__ rowptr, const int* __restrict__ cols,
                         const float* __restrict__ ssrc, const float* __restrict__ sdst,
                         const ushort_t* __restrict__ hv,
                         const float* __restrict__ bng, const float* __restrict__ bnb,
                         const float* __restrict__ bnm, const float* __restrict__ bnv,
                         const float* __restrict__ sasrc, const float* __restrict__ sadst,
                         float* __restrict__ ossrc, float* __restrict__ osdst,
                         float* __restrict__ out, int n){
  __shared__ int    s_cv[4][64];
  __shared__ float4 s_ex[4][64];
  int wid = threadIdx.x >> 6;
  int node = blockIdx.x * 4 + wid;
  if (node >= n) return;
  int lane = threadIdx.x & 63;
  const unsigned* hv32 = (const unsigned*)hv;
  int s = rowptr[node], e = rowptr[node + 1];
  const float4 sq = *(const float4*)&ssrc[node * 4];
  int hd = lane >> 4;
  float s0 = 0.f, s1 = 0.f, s2 = 0.f, s3 = 0.f;
  float a0 = 0.f, a1 = 0.f;
  const float* exw = &s_ex[wid][0].x;
  for (int j0 = s; j0 < e; j0 += 64){
    int len = min(64, e - j0);
    int cv = 0;
    float e0 = 0.f, e1 = 0.f, e2 = 0.f, e3 = 0.f;
    if (lane < len){
      cv = cols[j0 + lane];
      float4 kd = *(const float4*)&sdst[cv * 4];
      e0 = __expf(leaky(sq.x + kd.x)); e1 = __expf(leaky(sq.y + kd.y));
      e2 = __expf(leaky(sq.z + kd.z)); e3 = __expf(leaky(sq.w + kd.w));
    }
    s0 += e0; s1 += e1; s2 += e2; s3 += e3;
    s_cv[wid][lane] = cv;
    s_ex[wid][lane] = make_float4(e0, e1, e2, e3);
    int k = 0;
    for (; k + 4 <= len; k += 4){
      int c0 = s_cv[wid][k],   c1 = s_cv[wid][k+1];
      int c2 = s_cv[wid][k+2], c3 = s_cv[wid][k+3];
      float l0 = exw[(k)   * 4 + hd], l1 = exw[(k+1) * 4 + hd];
      float l2 = exw[(k+2) * 4 + hd], l3 = exw[(k+3) * 4 + hd];
      unsigned p0 = hv32[c0 * 64 + lane], p1 = hv32[c1 * 64 + lane];
      unsigned p2 = hv32[c2 * 64 + lane], p3 = hv32[c3 * 64 + lane];
      a0 += l0 * bf_lo(p0); a1 += l0 * bf_hi(p0);
      a0 += l1 * bf_lo(p1); a1 += l1 * bf_hi(p1);
      a0 += l2 * bf_lo(p2); a1 += l2 * bf_hi(p2);
      a0 += l3 * bf_lo(p3); a1 += l3 * bf_hi(p3);
    }
    for (; k < len; ++k){
      int c = s_cv[wid][k];
      float l = exw[k * 4 + hd];
      unsigned p = hv32[c * 64 + lane];
      a0 += l * bf_lo(p); a1 += l * bf_hi(p);
    }
  }
  s0 = wred_sum(s0); s1 = wred_sum(s1);
  s2 = wred_sum(s2); s3 = wred_sum(s3);
  float i0 = 1.f / (s0 + 1e-16f), i1 = 1.f / (s1 + 1e-16f);
  float i2 = 1.f / (s2 + 1e-16f), i3 = 1.f / (s3 + 1e-16f);
  float ih = sel4(i0, i1, i2, i3, hd);
  a0 *= ih; a1 *= ih;
  int d0 = 2 * lane, d1 = 2 * lane + 1;
  float v0 = (a0 - bnm[d0]) * rsqrtf(bnv[d0] + BN_EPS) * bng[d0] + bnb[d0];
  float v1 = (a1 - bnm[d1]) * rsqrtf(bnv[d1] + BN_EPS) * bng[d1] + bnb[d1];
  float o0 = leaky(v0), o1 = leaky(v1);
  out[node * HID + d0] = o0;
  out[node * HID + d1] = o1;
  float ps = o0 * sasrc[d0] + o1 * sasrc[d1];
  float pd = o0 * sadst[d0] + o1 * sadst[d1];
  ps = wred_sum(ps);
  pd = wred_sum(pd);
  if (lane == 0){ ossrc[node] = ps; osdst[node] = pd; }
}

// ---------------- output head ----------------
__global__ void k_out(const float* __restrict__ o1, const float* __restrict__ Wo2,
                      const float* __restrict__ bo2, const float* __restrict__ x,
                      float* __restrict__ out, int n){
  int node = blockIdx.x * 4 + (threadIdx.x >> 6);
  if (node >= n) return;
  int lane = threadIdx.x & 63;
  float a = o1[node * HID + lane], b = o1[node * HID + 64 + lane];
  float p0 = a * Wo2[lane * 3 + 0] + b * Wo2[(lane + 64) * 3 + 0];
  float p1 = a * Wo2[lane * 3 + 1] + b * Wo2[(lane + 64) * 3 + 1];
  float p2 = a * Wo2[lane * 3 + 2] + b * Wo2[(lane + 64) * 3 + 2];
  p0 = wred_sum(p0); p1 = wred_sum(p1); p2 = wred_sum(p2);
  if (lane == 0){
    out[node * 3 + 0] = x[node * DIN + 15] + p0 + bo2[0];
    out[node * 3 + 1] = x[node * DIN + 16] + p1 + bo2[1];
    out[node * 3 + 2] = x[node * DIN + 17] + p2 + bo2[2];
  }
}

extern "C" void kernel_launch(void* const* d_in, const int* in_sizes, int n_in,
                              void* d_out, int out_size, void* d_ws, size_t ws_size,
                              hipStream_t stream){
  const float* x       = (const float*)d_in[0];
  const int*   ei      = (const int*)  d_in[1];
  const float* W_in    = (const float*)d_in[2];
  const float* b_in    = (const float*)d_in[3];
  const float* W_agg   = (const float*)d_in[4];
  const float* b_agg   = (const float*)d_in[5];
  const float* sh_Wv   = (const float*)d_in[6];
  const float* sh_b    = (const float*)d_in[7];
  const float* sh_asrc = (const float*)d_in[8];
  const float* sh_adst = (const float*)d_in[9];
  const float* mh_Wv   = (const float*)d_in[10];
  const float* mh_b    = (const float*)d_in[11];
  const float* mh_asrc = (const float*)d_in[12];
  const float* mh_adst = (const float*)d_in[13];
  const float* bn_g    = (const float*)d_in[14];
  const float* bn_bt   = (const float*)d_in[15];
  const float* bn_m    = (const float*)d_in[16];
  const float* bn_v    = (const float*)d_in[17];
  const float* W_o1    = (const float*)d_in[18];
  const float* b_o1    = (const float*)d_in[19];
  const float* W_o2    = (const float*)d_in[20];
  const float* b_o2    = (const float*)d_in[21];
  float* out = (float*)d_out;

  const int N = in_sizes[0] / DIN;
  const int E = in_sizes[1] / 2;
  const int* row = ei;
  const int* col = ei + E;

  char* w = (char*)d_ws;
  size_t off = 0;
  auto alloc = [&](size_t bytes) -> void* {
    void* p = w + off;
    off = (off + bytes + 255) & ~(size_t)255;
    return p;
  };
  int*      tmp    = (int*)     alloc((size_t)N * 4);
  int*      rowptr = (int*)     alloc((size_t)(N + 1) * 4);
  int*      cols_s = (int*)     alloc((size_t)E * 4);
  int*      rank   = (int*)     alloc((size_t)E * 4);
  int*      bsum   = (int*)     alloc((size_t)1024 * 4);
  float*    nmean  = (float*)   alloc((size_t)N * DIN * 4);
  float*    ssrcA  = (float*)   alloc((size_t)N * 4);
  float*    sdstA  = (float*)   alloc((size_t)N * 4);
  float*    ssrcB  = (float*)   alloc((size_t)N * 4 * 4);
  float*    sdstB  = (float*)   alloc((size_t)N * 4 * 4);
  ushort_t* wt0    = (ushort_t*)alloc((size_t)HID * HID * 2);
  ushort_t* wt1    = (ushort_t*)alloc((size_t)HID * HID * 2);
  ushort_t* wt2    = (ushort_t*)alloc((size_t)HID * HID * 2);
  ushort_t* wt3    = (ushort_t*)alloc((size_t)HID * HID * 2);
  float*    buf0   = (float*)   alloc((size_t)N * HID * 4);
  float*    buf1   = (float*)   alloc((size_t)N * HID * 4);
  float*    buf2   = (float*)   alloc((size_t)N * HID * 4);
  ushort_t* hvb    = (ushort_t*)alloc((size_t)N * HID * 2);

  const int eb = (E + 255) / 256;
  const int nb4 = (N + 3) / 4;
  const int gb = (N + 63) / 64;
  const int nsb = (N + SCHUNK - 1) / SCHUNK;

  // CSR build (one atomic pass)
  hipMemsetAsync(tmp, 0, (size_t)N * 4, stream);
  k_deg_rank<<<eb, 256, 0, stream>>>(row, tmp, rank, E);
  k_scan1<<<nsb, 256, 0, stream>>>(tmp, bsum, N);
  k_scan2<<<1, 64, 0, stream>>>(bsum, nsb);
  k_scan3<<<nsb, 256, 0, stream>>>(tmp, bsum, rowptr, N);
  k_scatter<<<eb, 256, 0, stream>>>(row, col, rowptr, rank, cols_s, E);

  // weight prep (bf16, transposed)
  k_wt_sh<<<64, 256, 0, stream>>>(sh_Wv, wt0);
  k_wt_mh<<<64, 256, 0, stream>>>(mh_Wv, wt1);
  k_wt_sh<<<64, 256, 0, stream>>>(sh_Wv + HID * HID, wt2);
  k_wt_sh<<<64, 256, 0, stream>>>(W_o1, wt3);

  // neighbor mean + input projection (+layer0 sh scores) -> buf0
  k_nmean<<<nb4, 256, 0, stream>>>(x, rowptr, cols_s, nmean, N);
  k_h_in<<<nb4, 256, 0, stream>>>(x, nmean, W_in, b_in, W_agg, b_agg,
                                  sh_asrc, sh_adst, ssrcA, sdstA, buf0, N);

  // layer 0: single-head, residual buf0, bn[0] -> buf1 (+mh scores)
  k_gemm_mfma<<<gb, 256, 0, stream>>>(buf0, wt0, sh_b, hvb, nullptr, N, 2);
  k_agg_sh<<<nb4, 256, 0, stream>>>(rowptr, cols_s, ssrcA, sdstA, hvb, buf0,
                                    bn_g, bn_bt, bn_m, bn_v,
                                    mh_asrc, mh_adst, ssrcB, sdstB, buf1, N);

  // layer 1: multi-head, bn[1], no residual -> buf0 (+layer2 sh scores)
  k_gemm_mfma<<<gb, 256, 0, stream>>>(buf1, wt1, mh_b, hvb, nullptr, N, 2);
  k_agg_mh<<<nb4, 256, 0, stream>>>(rowptr, cols_s, ssrcB, sdstB, hvb,
                                    bn_g + HID, bn_bt + HID, bn_m + HID, bn_v + HID,
                                    sh_asrc + HID, sh_adst + HID, ssrcA, sdstA, buf0, N);

  // layer 2: single-head, residual buf0, bn[2] -> buf1 (no fused scores)
  k_gemm_mfma<<<gb, 256, 0, stream>>>(buf0, wt2, sh_b + HID, hvb, nullptr, N, 2);
  k_agg_sh<<<nb4, 256, 0, stream>>>(rowptr, cols_s, ssrcA, sdstA, hvb, buf0,
                                    bn_g + 2 * HID, bn_bt + 2 * HID, bn_m + 2 * HID, bn_v + 2 * HID,
                                    nullptr, nullptr, nullptr, nullptr, buf1, N);

  // output head
  k_gemm_mfma<<<gb, 256, 0, stream>>>(buf1, wt3, b_o1, nullptr, buf2, N, 1);
  k_out<<<nb4, 256, 0, stream>>>(buf2, W_o2, b_o2, x, out, N);
}